// Round 13
// baseline (373.662 us; speedup 1.0000x reference)
//
#include <hip/hip_runtime.h>
#include <hip/hip_bf16.h>
#include <cmath>

typedef unsigned short u16;
typedef __attribute__((ext_vector_type(8))) short short8;
typedef __attribute__((ext_vector_type(4))) float float4v;
#define LN_EPS 1e-5f

__device__ __forceinline__ float us2f(u16 u) {
    return __uint_as_float(((unsigned int)u) << 16);
}
__device__ __forceinline__ u16 f2us(float f) {
    __hip_bfloat16 h = __float2bfloat16(f);
    return *(u16*)&h;
}

__global__ __launch_bounds__(256) void sentinel_kernel(float* out, float v) {
    out[blockIdx.x * 256 + threadIdx.x] = v;
}

// ---------------------------------------------------------------------------
// qkv11: FUSED Q/K/V per block — X (E+posenc, hi/lo) staged ONCE per k-tile,
// three GEMMs against it. Fragment-contiguous K/V epilogues. Block (0,0)
// also dumps the freq table to ws for ln1. grid (64 mb, 8 h).
// ---------------------------------------------------------------------------
__global__ __launch_bounds__(256) void qkv11_kernel(const float* __restrict__ E,
                                                    const float* __restrict__ Wq,
                                                    const float* __restrict__ Wk,
                                                    const float* __restrict__ Wv,
                                                    float* __restrict__ Qcat,
                                                    u16* __restrict__ Khi,
                                                    u16* __restrict__ Klo,
                                                    u16* __restrict__ Vt,
                                                    double* __restrict__ Ftab) {
    const int h = blockIdx.y;
    const float* W0 = Wq + (long)h * 512 * 64;
    const float* W1 = Wk + (long)h * 512 * 64;
    const float* W2 = Wv + (long)h * 512 * 64;

    __shared__ u16 sAh[64][72], sAl[64][72];
    __shared__ u16 sBh[3][64][72], sBl[3][64][72];
    __shared__ double sFreqRev[512];

    const int t = threadIdx.x;
    const int w = t >> 6, l = t & 63;
    const int quad = l >> 4, l16 = l & 15;
    const int mw = w * 16;
    const int m0 = blockIdx.x * 64;

    {
        const double c = -9.210340371976184 / 512.0;  // -ln(10000)/512
        sFreqRev[t] = exp((double)(t & ~1) * c) * 0.15915494309189535;
        sFreqRev[t + 256] =
            exp((double)((t + 256) & ~1) * c) * 0.15915494309189535;
    }
    __syncthreads();
    if (blockIdx.x == 0 && blockIdx.y == 0) {
        Ftab[t] = sFreqRev[t];
        Ftab[t + 256] = sFreqRev[t + 256];
    }

    const int ar = t >> 2, ac = (t & 3) << 4;   // A staging: row, 16-col base
    const double posd = (double)(m0 + ar);
    const int brow4 = (t >> 4) << 2;            // B staging: 4 k-rows base
    const int bnc = (t & 15) << 2;              // B staging: 4 n-cols base

    float4v acc[3][4];
    #pragma unroll
    for (int ty = 0; ty < 3; ++ty)
        #pragma unroll
        for (int nt = 0; nt < 4; ++nt) acc[ty][nt] = (float4v){0.f, 0.f, 0.f, 0.f};

    for (int k0 = 0; k0 < 512; k0 += 64) {
        // ---- stage A = X[m0+ar][k0+ac .. +15] split hi/lo (ONCE for 3 GEMMs)
        #pragma unroll
        for (int u = 0; u < 4; ++u) {
            float4 ev = *(const float4*)(E + (long)(m0 + ar) * 512 + k0 + ac + 4 * u);
            float xs[4] = {ev.x, ev.y, ev.z, ev.w};
            ushort4 hh, ll;
            u16* hp = (u16*)&hh; u16* lp = (u16*)&ll;
            #pragma unroll
            for (int j = 0; j < 4; ++j) {
                const int col = k0 + ac + 4 * u + j;   // parity == j&1
                double rev = posd * sFreqRev[col];
                float fr = (float)(rev - floor(rev));
                float ang = 6.28318530717958647692f * fr;
                float pe = (j & 1) ? __cosf(ang) : __sinf(ang);
                float x = xs[j] + pe;
                u16 hi = f2us(x);
                hp[j] = hi;
                lp[j] = f2us(x - us2f(hi));
            }
            *(ushort4*)&sAh[ar][ac + 4 * u] = hh;
            *(ushort4*)&sAl[ar][ac + 4 * u] = ll;
        }
        // ---- stage B for 3 types (float4 reads, ushort4 writes along k)
        #pragma unroll
        for (int ty = 0; ty < 3; ++ty) {
            const float* W = (ty == 0 ? W0 : ty == 1 ? W1 : W2);
            float wv4[4][4];
            #pragma unroll
            for (int u = 0; u < 4; ++u)
                *(float4*)&wv4[u][0] =
                    *(const float4*)(W + (long)(k0 + brow4 + u) * 64 + bnc);
            #pragma unroll
            for (int j = 0; j < 4; ++j) {
                ushort4 hh, ll;
                #pragma unroll
                for (int u = 0; u < 4; ++u) {
                    u16 hi = f2us(wv4[u][j]);
                    ((u16*)&hh)[u] = hi;
                    ((u16*)&ll)[u] = f2us(wv4[u][j] - us2f(hi));
                }
                *(ushort4*)&sBh[ty][bnc + j][brow4] = hh;
                *(ushort4*)&sBl[ty][bnc + j][brow4] = ll;
            }
        }
        __syncthreads();
        #pragma unroll
        for (int kc = 0; kc < 2; ++kc) {
            short8 ah = *(const short8*)&sAh[mw + l16][kc * 32 + quad * 8];
            short8 al = *(const short8*)&sAl[mw + l16][kc * 32 + quad * 8];
            #pragma unroll
            for (int ty = 0; ty < 3; ++ty)
                #pragma unroll
                for (int nt = 0; nt < 4; ++nt) {
                    short8 bh = *(const short8*)&sBh[ty][nt * 16 + l16][kc * 32 + quad * 8];
                    short8 bl = *(const short8*)&sBl[ty][nt * 16 + l16][kc * 32 + quad * 8];
                    acc[ty][nt] = __builtin_amdgcn_mfma_f32_16x16x32_bf16(ah, bh, acc[ty][nt], 0, 0, 0);
                    acc[ty][nt] = __builtin_amdgcn_mfma_f32_16x16x32_bf16(ah, bl, acc[ty][nt], 0, 0, 0);
                    acc[ty][nt] = __builtin_amdgcn_mfma_f32_16x16x32_bf16(al, bh, acc[ty][nt], 0, 0, 0);
                }
        }
        __syncthreads();
    }

    // ---- epilogue Q (f32 -> Qcat)
    #pragma unroll
    for (int nt = 0; nt < 4; ++nt)
        #pragma unroll
        for (int rr = 0; rr < 4; ++rr) {
            const int row = m0 + mw + quad * 4 + rr;
            Qcat[(long)row * 512 + h * 64 + nt * 16 + l16] = acc[0][nt][rr];
        }
    // ---- epilogue K (fragment-contiguous hi/lo)
    {
        const int kb = m0 >> 6;
        #pragma unroll
        for (int nt = 0; nt < 4; ++nt) {
            const int fkc = nt >> 1;
            const int fquad = ((nt & 1) << 1) + (l16 >> 3);
            const int fe = l16 & 7;
            const long fbase = ((long)(h * 64 + kb) * 8 + fkc * 4 + w) * 512 +
                               fquad * 128 + fe;
            #pragma unroll
            for (int rr = 0; rr < 4; ++rr) {
                const long off = fbase + (quad * 4 + rr) * 8;
                float v = acc[1][nt][rr];
                u16 hi = f2us(v);
                Khi[off] = hi;
                Klo[off] = f2us(v - us2f(hi));
            }
        }
    }
    // ---- epilogue V (fragment-contiguous V^T)
    {
        const int kb = m0 >> 6;
        const int fkc = w >> 1;
        const int fquad = ((w & 1) << 1) + (quad >> 1);
        const int fe0 = (quad & 1) * 4;
        #pragma unroll
        for (int nt = 0; nt < 4; ++nt) {
            const long off = ((long)(h * 64 + kb) * 8 + fkc * 4 + nt) * 512 +
                             (fquad * 16 + l16) * 8 + fe0;
            ushort4 o;
            o.x = f2us(acc[2][nt][0]); o.y = f2us(acc[2][nt][1]);
            o.z = f2us(acc[2][nt][2]); o.w = f2us(acc[2][nt][3]);
            *(ushort4*)(Vt + off) = o;
        }
    }
}

// ---------------------------------------------------------------------------
// flash19: flash14 body, grid 512 -> 2 blocks/CU (4 waves/SIMD TLP).
// Each block: 64 q-rows, 8 waves: wq = w&1 (2 q-groups of 32 rows),
// ksec = w>>1 (4-way split-K, 16 kb each). Same per-CU K/V traffic as
// flash14, half the serial iters, double the TLP. Merge buffers ALIAS sP
// (dead after loop; extra barrier guards) -> LDS 54 KB -> 2 blocks/CU.
// All blocks on an XCD share one head (bid&7 == XCD id). VGPR 112 <= 128.
// ---------------------------------------------------------------------------
__global__ __launch_bounds__(512, 2) void flash19_kernel(const u16* __restrict__ Khi,
                                                         const u16* __restrict__ Klo,
                                                         const u16* __restrict__ Vt,
                                                         float* __restrict__ QZ) {
    const int bid = blockIdx.x;
    const int h = bid & 7;       // XCD-colocated heads
    const int qb = bid >> 3;     // 0..63

    // 54 KB union: sP (loop) / merge buffers (after loop)
    __shared__ __align__(16) char smem[55296];
    u16 (*sP)[32][72] = reinterpret_cast<u16(*)[32][72]>(smem);   // [8][32][72]
    float* mAccF = (float*)smem;              // [3][2][2][4][64][4] = 49152 B
    float* mMLF = (float*)(smem + 49152);     // [3][2][2][2][64]   =  6144 B

    const int t = threadIdx.x;
    const int w = t >> 6;          // 0..7
    const int wq = w & 1;          // q-row group (2 x 32 rows)
    const int ksec = w >> 1;       // K-range quarter (0..3)
    const int l = t & 63;
    const int quad = l >> 4;
    const int l16 = l & 15;
    const int mrow0 = qb * 64 + wq * 32;   // wave's first q-row

    // ---- Q fragments in registers (x0.125, hi/lo split), [kc][mf]
    short8 qh[2][2], ql[2][2];
    #pragma unroll
    for (int mf = 0; mf < 2; ++mf)
        #pragma unroll
        for (int kc = 0; kc < 2; ++kc) {
            const float* qp = QZ + (long)(mrow0 + mf * 16 + l16) * 512 + h * 64 +
                              kc * 32 + quad * 8;
            float4 qa = *(const float4*)qp;
            float4 qb4 = *(const float4*)(qp + 4);
            float qv[8] = {qa.x, qa.y, qa.z, qa.w, qb4.x, qb4.y, qb4.z, qb4.w};
            #pragma unroll
            for (int i = 0; i < 8; ++i) {
                float f = qv[i] * 0.125f;
                u16 hi = f2us(f);
                qh[kc][mf][i] = (short)hi;
                ql[kc][mf][i] = (short)f2us(f - us2f(hi));
            }
        }

    const u16* KH = Khi + (long)h * 262144;
    const u16* KL = Klo + (long)h * 262144;
    const u16* VT = Vt + (long)h * 262144;
    const int lo8 = l << 3;   // lane offset in u16 units (16B per lane)
    const int kb0 = ksec * 16;

    float m_i[2] = {-INFINITY, -INFINITY};
    float l_i[2] = {0.0f, 0.0f};
    float4v acc[2][4];
    #pragma unroll
    for (int mf = 0; mf < 2; ++mf)
        #pragma unroll
        for (int nt = 0; nt < 4; ++nt) acc[mf][nt] = (float4v){0.f, 0.f, 0.f, 0.f};

    for (int kb = kb0; kb < kb0 + 16; ++kb) {
        const long fb = (long)kb * 8;
        short8 kh_[8], kl_[8], vv_[8];
        #pragma unroll
        for (int f = 0; f < 8; ++f)
            kh_[f] = *(const short8*)(KH + (fb + f) * 512 + lo8);
        #pragma unroll
        for (int f = 0; f < 8; ++f)
            kl_[f] = *(const short8*)(KL + (fb + f) * 512 + lo8);
        #pragma unroll
        for (int f = 0; f < 8; ++f)
            vv_[f] = *(const short8*)(VT + (fb + f) * 512 + lo8);

        float4v s[2][4];
        #pragma unroll
        for (int mf = 0; mf < 2; ++mf)
            #pragma unroll
            for (int nt = 0; nt < 4; ++nt) s[mf][nt] = (float4v){0.f, 0.f, 0.f, 0.f};

        __builtin_amdgcn_s_setprio(1);
        #pragma unroll
        for (int mf = 0; mf < 2; ++mf) {
            #pragma unroll
            for (int kc = 0; kc < 2; ++kc)
                #pragma unroll
                for (int nt = 0; nt < 4; ++nt)
                    s[mf][nt] = __builtin_amdgcn_mfma_f32_16x16x32_bf16(
                        kh_[kc * 4 + nt], qh[kc][mf], s[mf][nt], 0, 0, 0);
            #pragma unroll
            for (int kc = 0; kc < 2; ++kc)
                #pragma unroll
                for (int nt = 0; nt < 4; ++nt)
                    s[mf][nt] = __builtin_amdgcn_mfma_f32_16x16x32_bf16(
                        kh_[kc * 4 + nt], ql[kc][mf], s[mf][nt], 0, 0, 0);
            #pragma unroll
            for (int kc = 0; kc < 2; ++kc)
                #pragma unroll
                for (int nt = 0; nt < 4; ++nt)
                    s[mf][nt] = __builtin_amdgcn_mfma_f32_16x16x32_bf16(
                        kl_[kc * 4 + nt], qh[kc][mf], s[mf][nt], 0, 0, 0);
        }
        __builtin_amdgcn_s_setprio(0);

        #pragma unroll
        for (int mf = 0; mf < 2; ++mf) {
            float x0 = fmaxf(fmaxf(s[mf][0][0], s[mf][0][1]),
                             fmaxf(s[mf][0][2], s[mf][0][3]));
            float x1 = fmaxf(fmaxf(s[mf][1][0], s[mf][1][1]),
                             fmaxf(s[mf][1][2], s[mf][1][3]));
            float x2 = fmaxf(fmaxf(s[mf][2][0], s[mf][2][1]),
                             fmaxf(s[mf][2][2], s[mf][2][3]));
            float x3 = fmaxf(fmaxf(s[mf][3][0], s[mf][3][1]),
                             fmaxf(s[mf][3][2], s[mf][3][3]));
            float rm = fmaxf(fmaxf(x0, x1), fmaxf(x2, x3));
            rm = fmaxf(rm, __shfl_xor(rm, 16, 64));
            rm = fmaxf(rm, __shfl_xor(rm, 32, 64));
            const float nm = fmaxf(m_i[mf], rm);
            const float al = __expf(m_i[mf] - nm);
            float p[4][4];
            #pragma unroll
            for (int nt = 0; nt < 4; ++nt)
                #pragma unroll
                for (int rr = 0; rr < 4; ++rr)
                    p[nt][rr] = __expf(s[mf][nt][rr] - nm);
            float y0 = (p[0][0] + p[0][1]) + (p[0][2] + p[0][3]);
            float y1 = (p[1][0] + p[1][1]) + (p[1][2] + p[1][3]);
            float y2 = (p[2][0] + p[2][1]) + (p[2][2] + p[2][3]);
            float y3 = (p[3][0] + p[3][1]) + (p[3][2] + p[3][3]);
            float ps = (y0 + y1) + (y2 + y3);
            ps += __shfl_xor(ps, 16, 64);
            ps += __shfl_xor(ps, 32, 64);
            l_i[mf] = l_i[mf] * al + ps;
            m_i[mf] = nm;
            #pragma unroll
            for (int nt = 0; nt < 4; ++nt) {
                acc[mf][nt][0] *= al; acc[mf][nt][1] *= al;
                acc[mf][nt][2] *= al; acc[mf][nt][3] *= al;
            }
            #pragma unroll
            for (int nt = 0; nt < 4; ++nt) {
                ushort4 pk;
                pk.x = f2us(p[nt][0]); pk.y = f2us(p[nt][1]);
                pk.z = f2us(p[nt][2]); pk.w = f2us(p[nt][3]);
                *(ushort4*)&sP[w][mf * 16 + l16][nt * 16 + quad * 4] = pk;
            }
        }

        __builtin_amdgcn_s_setprio(1);
        #pragma unroll
        for (int mf = 0; mf < 2; ++mf)
            #pragma unroll
            for (int kc = 0; kc < 2; ++kc) {
                short8 aP = *(const short8*)&sP[w][mf * 16 + l16][kc * 32 + quad * 8];
                #pragma unroll
                for (int nt = 0; nt < 4; ++nt)
                    acc[mf][nt] = __builtin_amdgcn_mfma_f32_16x16x32_bf16(
                        vv_[kc * 4 + nt], aP, acc[mf][nt], 0, 0, 0);
            }
        __builtin_amdgcn_s_setprio(0);
    }

    // ---- barrier: all waves done with sP before merge buffers alias it
    __syncthreads();

    // ---- 4-way split-K merge: ksec 1..3 publish, ksec 0 combines.
    if (ksec >= 1) {
        const int pub = ksec - 1;
        #pragma unroll
        for (int mf = 0; mf < 2; ++mf) {
            const int bse = ((pub * 2 + wq) * 2 + mf);
            #pragma unroll
            for (int nt = 0; nt < 4; ++nt)
                *(float4*)&mAccF[((bse * 4 + nt) * 64 + l) * 4] =
                    make_float4(acc[mf][nt][0], acc[mf][nt][1],
                                acc[mf][nt][2], acc[mf][nt][3]);
            mMLF[(bse * 2 + 0) * 64 + l] = m_i[mf];
            mMLF[(bse * 2 + 1) * 64 + l] = l_i[mf];
        }
    }
    __syncthreads();
    if (ksec == 0) {
        #pragma unroll
        for (int mf = 0; mf < 2; ++mf) {
            float nm = m_i[mf];
            #pragma unroll
            for (int pub = 0; pub < 3; ++pub) {
                const int bse = ((pub * 2 + wq) * 2 + mf);
                nm = fmaxf(nm, mMLF[(bse * 2 + 0) * 64 + l]);
            }
            const float a0 = __expf(m_i[mf] - nm);
            float lsum = l_i[mf] * a0;
            float ax[3];
            #pragma unroll
            for (int pub = 0; pub < 3; ++pub) {
                const int bse = ((pub * 2 + wq) * 2 + mf);
                ax[pub] = __expf(mMLF[(bse * 2 + 0) * 64 + l] - nm);
                lsum += mMLF[(bse * 2 + 1) * 64 + l] * ax[pub];
            }
            const float inv = 1.0f / lsum;
            #pragma unroll
            for (int nt = 0; nt < 4; ++nt) {
                float ox = acc[mf][nt][0] * a0;
                float oy = acc[mf][nt][1] * a0;
                float oz = acc[mf][nt][2] * a0;
                float ow = acc[mf][nt][3] * a0;
                #pragma unroll
                for (int pub = 0; pub < 3; ++pub) {
                    const int bse = ((pub * 2 + wq) * 2 + mf);
                    float4 o1 = *(float4*)&mAccF[((bse * 4 + nt) * 64 + l) * 4];
                    ox += o1.x * ax[pub]; oy += o1.y * ax[pub];
                    oz += o1.z * ax[pub]; ow += o1.w * ax[pub];
                }
                float4 o = make_float4(ox * inv, oy * inv, oz * inv, ow * inv);
                *(float4*)(QZ + (long)(mrow0 + mf * 16 + l16) * 512 + h * 64 +
                           nt * 16 + quad * 4) = o;
            }
        }
    }
}

// ---------------------------------------------------------------------------
// wo2 (MFMA): tmp = Zcat @ WO via bf16 hi/lo 3-product.  grid (8 nb, 64 mb).
// ---------------------------------------------------------------------------
__global__ __launch_bounds__(256) void wo2_kernel(const float* __restrict__ A,
                                                  const float* __restrict__ B,
                                                  float* __restrict__ C) {
    __shared__ u16 sAh[64][72], sAl[64][72];
    __shared__ u16 sBh[64][72], sBl[64][72];
    const int t = threadIdx.x;
    const int w = t >> 6, l = t & 63;
    const int quad = l >> 4, l16 = l & 15;
    const int mw = w * 16;
    const int m0 = blockIdx.y * 64, n0 = blockIdx.x * 64;
    const int ar = t >> 2, ac = (t & 3) << 4;

    float4v acc[4];
    #pragma unroll
    for (int nt = 0; nt < 4; ++nt) acc[nt] = (float4v){0.f, 0.f, 0.f, 0.f};

    for (int k0 = 0; k0 < 512; k0 += 64) {
        #pragma unroll
        for (int u = 0; u < 4; ++u) {
            float4 av = *(const float4*)(A + (long)(m0 + ar) * 512 + k0 + ac + 4 * u);
            float xs[4] = {av.x, av.y, av.z, av.w};
            ushort4 hh, ll;
            u16* hp = (u16*)&hh; u16* lp = (u16*)&ll;
            #pragma unroll
            for (int j = 0; j < 4; ++j) {
                u16 hi = f2us(xs[j]);
                hp[j] = hi;
                lp[j] = f2us(xs[j] - us2f(hi));
            }
            *(ushort4*)&sAh[ar][ac + 4 * u] = hh;
            *(ushort4*)&sAl[ar][ac + 4 * u] = ll;
        }
        {
            const int kr = t >> 2, nc = (t & 3) << 4;
            #pragma unroll
            for (int u = 0; u < 4; ++u) {
                float4 wv = *(const float4*)(B + (long)(k0 + kr) * 512 + n0 + nc + 4 * u);
                float ws4[4] = {wv.x, wv.y, wv.z, wv.w};
                #pragma unroll
                for (int j = 0; j < 4; ++j) {
                    const int n = nc + 4 * u + j;
                    u16 hi = f2us(ws4[j]);
                    sBh[n][kr] = hi;
                    sBl[n][kr] = f2us(ws4[j] - us2f(hi));
                }
            }
        }
        __syncthreads();
        #pragma unroll
        for (int kc = 0; kc < 2; ++kc) {
            short8 ah = *(const short8*)&sAh[mw + l16][kc * 32 + quad * 8];
            short8 al = *(const short8*)&sAl[mw + l16][kc * 32 + quad * 8];
            #pragma unroll
            for (int nt = 0; nt < 4; ++nt) {
                short8 bh = *(const short8*)&sBh[nt * 16 + l16][kc * 32 + quad * 8];
                short8 bl = *(const short8*)&sBl[nt * 16 + l16][kc * 32 + quad * 8];
                acc[nt] = __builtin_amdgcn_mfma_f32_16x16x32_bf16(ah, bh, acc[nt], 0, 0, 0);
                acc[nt] = __builtin_amdgcn_mfma_f32_16x16x32_bf16(ah, bl, acc[nt], 0, 0, 0);
                acc[nt] = __builtin_amdgcn_mfma_f32_16x16x32_bf16(al, bh, acc[nt], 0, 0, 0);
            }
        }
        __syncthreads();
    }
    #pragma unroll
    for (int nt = 0; nt < 4; ++nt)
        #pragma unroll
        for (int rr = 0; rr < 4; ++rr) {
            const int row = m0 + mw + quad * 4 + rr;
            C[(long)row * 512 + n0 + nt * 16 + l16] = acc[nt][rr];
        }
}

// ---------------------------------------------------------------------------
// ln1: Z1 = LN(tmp + E + posenc)*g + be -> d_out f32 AND Z1b bf16 (ws).
// posenc via precomputed freq table (no per-element double exp).
// ---------------------------------------------------------------------------
__global__ __launch_bounds__(256) void ln1_kernel(const float* __restrict__ tmp,
                                                  const float* __restrict__ E,
                                                  const float* __restrict__ g,
                                                  const float* __restrict__ be,
                                                  float* __restrict__ out,
                                                  u16* __restrict__ z1b,
                                                  const double* __restrict__ Ftab) {
    const int r = blockIdx.x, t = threadIdx.x;
    const long base = (long)r * 512;
    __shared__ float red[256];

    double rev0 = (double)r * Ftab[t];
    float fr0 = (float)(rev0 - floor(rev0));
    float ang0 = 6.28318530717958647692f * fr0;
    float pe0 = (t & 1) ? __cosf(ang0) : __sinf(ang0);
    double rev1 = (double)r * Ftab[t + 256];
    float fr1 = (float)(rev1 - floor(rev1));
    float ang1 = 6.28318530717958647692f * fr1;
    float pe1 = (t & 1) ? __cosf(ang1) : __sinf(ang1);

    float v0 = tmp[base + t] + E[base + t] + pe0;
    float v1 = tmp[base + t + 256] + E[base + t + 256] + pe1;

    red[t] = v0 + v1; __syncthreads();
    for (int s2 = 128; s2 > 0; s2 >>= 1) {
        if (t < s2) red[t] += red[t + s2];
        __syncthreads();
    }
    const float mean = red[0] * (1.0f / 512.0f);
    __syncthreads();
    float d0 = v0 - mean, d1 = v1 - mean;
    red[t] = d0 * d0 + d1 * d1; __syncthreads();
    for (int s2 = 128; s2 > 0; s2 >>= 1) {
        if (t < s2) red[t] += red[t + s2];
        __syncthreads();
    }
    const float rs = rsqrtf(red[0] * (1.0f / 512.0f) + LN_EPS);
    float o0 = d0 * rs * g[t] + be[t];
    float o1 = d1 * rs * g[t + 256] + be[t + 256];
    out[base + t] = o0;
    out[base + t + 256] = o1;
    z1b[base + t] = f2us(o0);
    z1b[base + t + 256] = f2us(o1);
}

// ---------------------------------------------------------------------------
// wtrans: dst[n][k] (bf16) = src[k][n] (f32).  grid (K/64, N/64).
// ---------------------------------------------------------------------------
__global__ __launch_bounds__(256) void wtrans_kernel(const float* __restrict__ src,
                                                     u16* __restrict__ dst,
                                                     int K, int N) {
    __shared__ float sT[64][65];
    const int t = threadIdx.x;
    const int k0 = blockIdx.x * 64, n0 = blockIdx.y * 64;
    #pragma unroll
    for (int c = 0; c < 4; ++c) {
        const int r = (t >> 4) + c * 16;
        float4 v = *(const float4*)(src + (long)(k0 + r) * N + n0 + ((t & 15) << 2));
        sT[r][((t & 15) << 2) + 0] = v.x;
        sT[r][((t & 15) << 2) + 1] = v.y;
        sT[r][((t & 15) << 2) + 2] = v.z;
        sT[r][((t & 15) << 2) + 3] = v.w;
    }
    __syncthreads();
    const int n = t >> 2, kc = (t & 3) << 4;
    #pragma unroll
    for (int u = 0; u < 4; ++u) {
        ushort4 o;
        o.x = f2us(sT[kc + 4 * u + 0][n]);
        o.y = f2us(sT[kc + 4 * u + 1][n]);
        o.z = f2us(sT[kc + 4 * u + 2][n]);
        o.w = f2us(sT[kc + 4 * u + 3][n]);
        *(ushort4*)(dst + (long)(n0 + n) * K + k0 + kc + 4 * u) = o;
    }
}

// ---------------------------------------------------------------------------
// ffn1 (MFMA): Hff = relu(Z1b @ W1t^T + b1) -> bf16.
// ---------------------------------------------------------------------------
__global__ __launch_bounds__(256) void ffn1_kernel(const u16* __restrict__ A,
                                                   const u16* __restrict__ Bt,
                                                   const float* __restrict__ b1,
                                                   u16* __restrict__ C,
                                                   int m_base) {
    __shared__ u16 sA[64][72], sB[64][72];
    const int t = threadIdx.x;
    const int w = t >> 6, l = t & 63, quad = l >> 4, l16 = l & 15;
    const int mw = w * 16;
    const int m0 = m_base + blockIdx.y * 64, n0 = blockIdx.x * 64;
    const int r = t >> 2, cc = (t & 3) << 4;

    float4v acc[4];
    #pragma unroll
    for (int nt = 0; nt < 4; ++nt) acc[nt] = (float4v){0.f, 0.f, 0.f, 0.f};

    for (int kt = 0; kt < 512; kt += 64) {
        const long aoff = (long)(m0 + r) * 512 + kt + cc;
        *(uint4*)&sA[r][cc]     = *(const uint4*)(A + aoff);
        *(uint4*)&sA[r][cc + 8] = *(const uint4*)(A + aoff + 8);
        const long boff = (long)(n0 + r) * 512 + kt + cc;
        *(uint4*)&sB[r][cc]     = *(const uint4*)(Bt + boff);
        *(uint4*)&sB[r][cc + 8] = *(const uint4*)(Bt + boff + 8);
        __syncthreads();
        #pragma unroll
        for (int kc = 0; kc < 2; ++kc) {
            short8 a = *(const short8*)&sA[mw + l16][kc * 32 + quad * 8];
            #pragma unroll
            for (int nt = 0; nt < 4; ++nt) {
                short8 b = *(const short8*)&sB[nt * 16 + l16][kc * 32 + quad * 8];
                acc[nt] = __builtin_amdgcn_mfma_f32_16x16x32_bf16(a, b, acc[nt], 0, 0, 0);
            }
        }
        __syncthreads();
    }
    #pragma unroll
    for (int rr = 0; rr < 4; ++rr) {
        const int row = blockIdx.y * 64 + mw + quad * 4 + rr;  // chunk-local
        #pragma unroll
        for (int nt = 0; nt < 4; ++nt) {
            const int col = n0 + nt * 16 + l16;
            float v = acc[nt][rr] + b1[col];
            C[(long)row * 2048 + col] = f2us(fmaxf(v, 0.0f));
        }
    }
}

// ---------------------------------------------------------------------------
// ffn2 (MFMA): U = Hff @ W2t^T + b2 -> f32.  Tile 32x64, grid (8 nb, 32 mb)
// = 256 blocks/chunk (verified: ~2x vs 128-block version).
// ---------------------------------------------------------------------------
__global__ __launch_bounds__(256) void ffn2_kernel(const u16* __restrict__ A,
                                                   const u16* __restrict__ Bt,
                                                   const float* __restrict__ b2,
                                                   float* __restrict__ U) {
    __shared__ u16 sA[32][72], sB[64][72];
    const int t = threadIdx.x;
    const int w = t >> 6, l = t & 63, quad = l >> 4, l16 = l & 15;
    const int mf = (w & 1) << 4;     // row-frag base within 32
    const int nh = (w >> 1) << 5;    // col-half base within 64
    const int m0 = blockIdx.y * 32, n0 = blockIdx.x * 64;
    const int ra = t >> 3, ca = (t & 7) << 3;   // A staging: 32x64, 1 uint4/thr
    const int rb = t >> 2, cb = (t & 3) << 4;   // B staging: 64x64, 2 uint4/thr

    float4v acc[2];
    acc[0] = (float4v){0.f, 0.f, 0.f, 0.f};
    acc[1] = (float4v){0.f, 0.f, 0.f, 0.f};

    for (int kt = 0; kt < 2048; kt += 64) {
        *(uint4*)&sA[ra][ca] =
            *(const uint4*)(A + (long)(m0 + ra) * 2048 + kt + ca);
        const long boff = (long)(n0 + rb) * 2048 + kt + cb;
        *(uint4*)&sB[rb][cb]     = *(const uint4*)(Bt + boff);
        *(uint4*)&sB[rb][cb + 8] = *(const uint4*)(Bt + boff + 8);
        __syncthreads();
        #pragma unroll
        for (int kc = 0; kc < 2; ++kc) {
            short8 a = *(const short8*)&sA[mf + l16][kc * 32 + quad * 8];
            #pragma unroll
            for (int nt = 0; nt < 2; ++nt) {
                short8 b = *(const short8*)&sB[nh + nt * 16 + l16][kc * 32 + quad * 8];
                acc[nt] = __builtin_amdgcn_mfma_f32_16x16x32_bf16(a, b, acc[nt], 0, 0, 0);
            }
        }
        __syncthreads();
    }
    #pragma unroll
    for (int rr = 0; rr < 4; ++rr) {
        const int row = m0 + mf + quad * 4 + rr;
        #pragma unroll
        for (int nt = 0; nt < 2; ++nt) {
            const int col = n0 + nh + nt * 16 + l16;
            U[(long)row * 512 + col] = acc[nt][rr] + b2[col];
        }
    }
}

// ---------------------------------------------------------------------------
// ln2: out = LN(U + Z1)*g + be (in place over Z1 rows).
// ---------------------------------------------------------------------------
__global__ __launch_bounds__(256) void ln2_kernel(const float* __restrict__ U,
                                                  const float* __restrict__ Z1,
                                                  const float* __restrict__ g,
                                                  const float* __restrict__ be,
                                                  float* __restrict__ out) {
    const int r = blockIdx.x, t = threadIdx.x;
    const long base = (long)r * 512;
    __shared__ float red[256];

    float v0 = U[base + t] + Z1[base + t];
    float v1 = U[base + t + 256] + Z1[base + t + 256];

    red[t] = v0 + v1; __syncthreads();
    for (int s2 = 128; s2 > 0; s2 >>= 1) {
        if (t < s2) red[t] += red[t + s2];
        __syncthreads();
    }
    const float mean = red[0] * (1.0f / 512.0f);
    __syncthreads();
    float d0 = v0 - mean, d1 = v1 - mean;
    red[t] = d0 * d0 + d1 * d1; __syncthreads();
    for (int s2 = 128; s2 > 0; s2 >>= 1) {
        if (t < s2) red[t] += red[t + s2];
        __syncthreads();
    }
    const float rs = rsqrtf(red[0] * (1.0f / 512.0f) + LN_EPS);
    out[base + t] = d0 * rs * g[t] + be[t];
    out[base + t + 256] = d1 * rs * g[t + 256] + be[t + 256];
}

// ---------------------------------------------------------------------------
// ws timeline (max 14 MB):
//   attention: Khi @0 (4) | Klo @4 (4) | Vt @8 (4) | Ftab @12 (4KB)
//   wo/ln1:    tmp @0 (8) | Z1b @8 (4) | Ftab @12 (4KB, live)
//   FFN:       W1t @0 (2) | W2t @2 (2) | Hff @4 (4/chunk) | U @12 (2/chunk)
// d_out: Qcat -> Zcat -> Z1 -> out (race-free phase overwrites).
// ---------------------------------------------------------------------------
extern "C" void kernel_launch(void* const* d_in, const int* in_sizes, int n_in,
                              void* d_out, int out_size, void* d_ws, size_t ws_size,
                              hipStream_t stream) {
    float* outf = (float*)d_out;

    static const int exp_sizes[13] = {2097152, 262144, 262144, 262144, 262144,
                                      1048576, 2048, 1048576, 512, 512, 512,
                                      512, 512};
    bool ok = (n_in == 13) && (out_size == 2097152) &&
              (ws_size >= (14ull << 20));
    if (ok) for (int i = 0; i < 13; ++i) if (in_sizes[i] != exp_sizes[i]) ok = false;
    if (!ok) { sentinel_kernel<<<16, 256, 0, stream>>>(outf, 1000.0f); return; }

    const float* E   = (const float*)d_in[0];
    const float* Wq  = (const float*)d_in[1];
    const float* Wk  = (const float*)d_in[2];
    const float* Wv  = (const float*)d_in[3];
    const float* WO  = (const float*)d_in[4];
    const float* W1  = (const float*)d_in[5];
    const float* b1  = (const float*)d_in[6];
    const float* W2  = (const float*)d_in[7];
    const float* b2  = (const float*)d_in[8];
    const float* g1  = (const float*)d_in[9];
    const float* be1 = (const float*)d_in[10];
    const float* g2  = (const float*)d_in[11];
    const float* be2 = (const float*)d_in[12];

    char* base = (char*)d_ws;
    u16*   Khi = (u16*)base;                     // 4 MB
    u16*   Klo = (u16*)(base + (4l << 20));      // 4 MB
    u16*   Vt  = (u16*)(base + (8l << 20));      // 4 MB
    double* Ftab = (double*)(base + (12l << 20)); // 4 KB (live thru ln1)
    float* tmp = (float*)base;                   // 8 MB (K dead)
    u16*   Z1b = (u16*)(base + (8l << 20));      // 4 MB (Vt dead)
    u16*   W1t = (u16*)base;                     // 2 MB (tmp dead)
    u16*   W2t = (u16*)(base + (2l << 20));      // 2 MB
    u16*   Hff = (u16*)(base + (4l << 20));      // 4 MB / chunk
    float* U   = (float*)(base + (12l << 20));   // 2 MB / chunk (Ftab dead)

    qkv11_kernel<<<dim3(64, 8), 256, 0, stream>>>(E, Wq, Wk, Wv, outf,
                                                  Khi, Klo, Vt, Ftab);
    flash19_kernel<<<dim3(512), 512, 0, stream>>>(Khi, Klo, Vt, outf);
    wo2_kernel<<<dim3(8, 64), 256, 0, stream>>>(outf, WO, tmp);
    ln1_kernel<<<4096, 256, 0, stream>>>(tmp, E, g1, be1, outf, Z1b, Ftab);
    wtrans_kernel<<<dim3(8, 32), 256, 0, stream>>>(W1, W1t, 512, 2048);
    wtrans_kernel<<<dim3(32, 8), 256, 0, stream>>>(W2, W2t, 2048, 512);

    for (int c = 0; c < 4; ++c) {
        ffn1_kernel<<<dim3(32, 16), 256, 0, stream>>>(Z1b, W1t, b1, Hff,
                                                      c * 1024);
        ffn2_kernel<<<dim3(8, 32), 256, 0, stream>>>(Hff, W2t, b2, U);
        ln2_kernel<<<1024, 256, 0, stream>>>(U, outf + (long)c * 1024 * 512,
                                             g2, be2,
                                             outf + (long)c * 1024 * 512);
    }
}

// Round 14
// 367.220 us; speedup vs baseline: 1.0175x; 1.0175x over previous
//
#include <hip/hip_runtime.h>
#include <hip/hip_bf16.h>
#include <cmath>

typedef unsigned short u16;
typedef __attribute__((ext_vector_type(8))) short short8;
typedef __attribute__((ext_vector_type(4))) float float4v;
#define LN_EPS 1e-5f

__device__ __forceinline__ float us2f(u16 u) {
    return __uint_as_float(((unsigned int)u) << 16);
}
__device__ __forceinline__ u16 f2us(float f) {
    __hip_bfloat16 h = __float2bfloat16(f);
    return *(u16*)&h;
}

// Fast posenc: double-precision argument reduction (exact for pos<4096),
// then hardware v_sin_f32/v_cos_f32.
__device__ __forceinline__ float posenc_f(int s, int d) {
    const double c = -9.210340371976184 / 512.0;  // -ln(10000)/512
    double freq_rev = exp((double)(d & ~1) * c) * 0.15915494309189535;
    double rev = (double)s * freq_rev;
    float fr = (float)(rev - floor(rev));
    float ang = 6.28318530717958647692f * fr;
    return (d & 1) ? __cosf(ang) : __sinf(ang);
}

__global__ __launch_bounds__(256) void sentinel_kernel(float* out, float v) {
    out[blockIdx.x * 256 + threadIdx.x] = v;
}

// ---------------------------------------------------------------------------
// qkv11: FUSED Q/K/V per block — X (E+posenc, hi/lo) staged ONCE per k-tile,
// three GEMMs against it. Fragment-contiguous K/V epilogues.
// grid (64 mb, 8 h).
// ---------------------------------------------------------------------------
__global__ __launch_bounds__(256) void qkv11_kernel(const float* __restrict__ E,
                                                    const float* __restrict__ Wq,
                                                    const float* __restrict__ Wk,
                                                    const float* __restrict__ Wv,
                                                    float* __restrict__ Qcat,
                                                    u16* __restrict__ Khi,
                                                    u16* __restrict__ Klo,
                                                    u16* __restrict__ Vt) {
    const int h = blockIdx.y;
    const float* W0 = Wq + (long)h * 512 * 64;
    const float* W1 = Wk + (long)h * 512 * 64;
    const float* W2 = Wv + (long)h * 512 * 64;

    __shared__ u16 sAh[64][72], sAl[64][72];
    __shared__ u16 sBh[3][64][72], sBl[3][64][72];
    __shared__ double sFreqRev[512];

    const int t = threadIdx.x;
    const int w = t >> 6, l = t & 63;
    const int quad = l >> 4, l16 = l & 15;
    const int mw = w * 16;
    const int m0 = blockIdx.x * 64;

    {
        const double c = -9.210340371976184 / 512.0;  // -ln(10000)/512
        sFreqRev[t] = exp((double)(t & ~1) * c) * 0.15915494309189535;
        sFreqRev[t + 256] =
            exp((double)((t + 256) & ~1) * c) * 0.15915494309189535;
    }
    __syncthreads();

    const int ar = t >> 2, ac = (t & 3) << 4;   // A staging: row, 16-col base
    const double posd = (double)(m0 + ar);
    const int brow4 = (t >> 4) << 2;            // B staging: 4 k-rows base
    const int bnc = (t & 15) << 2;              // B staging: 4 n-cols base

    float4v acc[3][4];
    #pragma unroll
    for (int ty = 0; ty < 3; ++ty)
        #pragma unroll
        for (int nt = 0; nt < 4; ++nt) acc[ty][nt] = (float4v){0.f, 0.f, 0.f, 0.f};

    for (int k0 = 0; k0 < 512; k0 += 64) {
        // ---- stage A = X[m0+ar][k0+ac .. +15] split hi/lo (ONCE for 3 GEMMs)
        #pragma unroll
        for (int u = 0; u < 4; ++u) {
            float4 ev = *(const float4*)(E + (long)(m0 + ar) * 512 + k0 + ac + 4 * u);
            float xs[4] = {ev.x, ev.y, ev.z, ev.w};
            ushort4 hh, ll;
            u16* hp = (u16*)&hh; u16* lp = (u16*)&ll;
            #pragma unroll
            for (int j = 0; j < 4; ++j) {
                const int col = k0 + ac + 4 * u + j;   // parity == j&1
                double rev = posd * sFreqRev[col];
                float fr = (float)(rev - floor(rev));
                float ang = 6.28318530717958647692f * fr;
                float pe = (j & 1) ? __cosf(ang) : __sinf(ang);
                float x = xs[j] + pe;
                u16 hi = f2us(x);
                hp[j] = hi;
                lp[j] = f2us(x - us2f(hi));
            }
            *(ushort4*)&sAh[ar][ac + 4 * u] = hh;
            *(ushort4*)&sAl[ar][ac + 4 * u] = ll;
        }
        // ---- stage B for 3 types (float4 reads, ushort4 writes along k)
        #pragma unroll
        for (int ty = 0; ty < 3; ++ty) {
            const float* W = (ty == 0 ? W0 : ty == 1 ? W1 : W2);
            float wv4[4][4];
            #pragma unroll
            for (int u = 0; u < 4; ++u)
                *(float4*)&wv4[u][0] =
                    *(const float4*)(W + (long)(k0 + brow4 + u) * 64 + bnc);
            #pragma unroll
            for (int j = 0; j < 4; ++j) {
                ushort4 hh, ll;
                #pragma unroll
                for (int u = 0; u < 4; ++u) {
                    u16 hi = f2us(wv4[u][j]);
                    ((u16*)&hh)[u] = hi;
                    ((u16*)&ll)[u] = f2us(wv4[u][j] - us2f(hi));
                }
                *(ushort4*)&sBh[ty][bnc + j][brow4] = hh;
                *(ushort4*)&sBl[ty][bnc + j][brow4] = ll;
            }
        }
        __syncthreads();
        #pragma unroll
        for (int kc = 0; kc < 2; ++kc) {
            short8 ah = *(const short8*)&sAh[mw + l16][kc * 32 + quad * 8];
            short8 al = *(const short8*)&sAl[mw + l16][kc * 32 + quad * 8];
            #pragma unroll
            for (int ty = 0; ty < 3; ++ty)
                #pragma unroll
                for (int nt = 0; nt < 4; ++nt) {
                    short8 bh = *(const short8*)&sBh[ty][nt * 16 + l16][kc * 32 + quad * 8];
                    short8 bl = *(const short8*)&sBl[ty][nt * 16 + l16][kc * 32 + quad * 8];
                    acc[ty][nt] = __builtin_amdgcn_mfma_f32_16x16x32_bf16(ah, bh, acc[ty][nt], 0, 0, 0);
                    acc[ty][nt] = __builtin_amdgcn_mfma_f32_16x16x32_bf16(ah, bl, acc[ty][nt], 0, 0, 0);
                    acc[ty][nt] = __builtin_amdgcn_mfma_f32_16x16x32_bf16(al, bh, acc[ty][nt], 0, 0, 0);
                }
        }
        __syncthreads();
    }

    // ---- epilogue Q (f32 -> Qcat)
    #pragma unroll
    for (int nt = 0; nt < 4; ++nt)
        #pragma unroll
        for (int rr = 0; rr < 4; ++rr) {
            const int row = m0 + mw + quad * 4 + rr;
            Qcat[(long)row * 512 + h * 64 + nt * 16 + l16] = acc[0][nt][rr];
        }
    // ---- epilogue K (fragment-contiguous hi/lo)
    {
        const int kb = m0 >> 6;
        #pragma unroll
        for (int nt = 0; nt < 4; ++nt) {
            const int fkc = nt >> 1;
            const int fquad = ((nt & 1) << 1) + (l16 >> 3);
            const int fe = l16 & 7;
            const long fbase = ((long)(h * 64 + kb) * 8 + fkc * 4 + w) * 512 +
                               fquad * 128 + fe;
            #pragma unroll
            for (int rr = 0; rr < 4; ++rr) {
                const long off = fbase + (quad * 4 + rr) * 8;
                float v = acc[1][nt][rr];
                u16 hi = f2us(v);
                Khi[off] = hi;
                Klo[off] = f2us(v - us2f(hi));
            }
        }
    }
    // ---- epilogue V (fragment-contiguous V^T)
    {
        const int kb = m0 >> 6;
        const int fkc = w >> 1;
        const int fquad = ((w & 1) << 1) + (quad >> 1);
        const int fe0 = (quad & 1) * 4;
        #pragma unroll
        for (int nt = 0; nt < 4; ++nt) {
            const long off = ((long)(h * 64 + kb) * 8 + fkc * 4 + nt) * 512 +
                             (fquad * 16 + l16) * 8 + fe0;
            ushort4 o;
            o.x = f2us(acc[2][nt][0]); o.y = f2us(acc[2][nt][1]);
            o.z = f2us(acc[2][nt][2]); o.w = f2us(acc[2][nt][3]);
            *(ushort4*)(Vt + off) = o;
        }
    }
}

// ---------------------------------------------------------------------------
// flash14: split-K flash (VERIFIED 87us, VGPR 112, no spill). 8 waves:
// wq = w&3 owns 32 q-rows, khalf = w>>2 owns half the K range. No prefetch
// registers (2 waves/SIMD TLP hides L2 latency). LDS padded >80 KB so only
// ONE block/CU fits. Tree reductions, wave-private sP, no in-loop barrier,
// end merge. grid 256, h = bid&7 for XCD colocation.
// ---------------------------------------------------------------------------
__global__ __launch_bounds__(512, 2) void flash14_kernel(const u16* __restrict__ Khi,
                                                         const u16* __restrict__ Klo,
                                                         const u16* __restrict__ Vt,
                                                         float* __restrict__ QZ) {
    const int bid = blockIdx.x;
    const int h = bid & 7;       // XCD-colocated heads
    const int qb = bid >> 3;

    __shared__ u16 sP[8][64][72];                 // 72 KB (padded: block/CU=1)
    __shared__ float mAcc[4][2][4][64][4];        // 32 KB, merge buffer
    __shared__ float mML[4][2][2][64];            // 4 KB, m/l merge

    const int t = threadIdx.x;
    const int w = t >> 6;          // 0..7
    const int wq = w & 3;          // q-row group
    const int khalf = w >> 2;      // K-range half
    const int l = t & 63;
    const int quad = l >> 4;
    const int l16 = l & 15;
    const int mrow0 = qb * 128 + wq * 32;   // wave's first q-row

    // ---- Q fragments in registers (x0.125, hi/lo split), [kc][mf]
    short8 qh[2][2], ql[2][2];
    #pragma unroll
    for (int mf = 0; mf < 2; ++mf)
        #pragma unroll
        for (int kc = 0; kc < 2; ++kc) {
            const float* qp = QZ + (long)(mrow0 + mf * 16 + l16) * 512 + h * 64 +
                              kc * 32 + quad * 8;
            float4 qa = *(const float4*)qp;
            float4 qb4 = *(const float4*)(qp + 4);
            float qv[8] = {qa.x, qa.y, qa.z, qa.w, qb4.x, qb4.y, qb4.z, qb4.w};
            #pragma unroll
            for (int i = 0; i < 8; ++i) {
                float f = qv[i] * 0.125f;
                u16 hi = f2us(f);
                qh[kc][mf][i] = (short)hi;
                ql[kc][mf][i] = (short)f2us(f - us2f(hi));
            }
        }

    const u16* KH = Khi + (long)h * 262144;
    const u16* KL = Klo + (long)h * 262144;
    const u16* VT = Vt + (long)h * 262144;
    const int lo8 = l << 3;   // lane offset in u16 units (16B per lane)
    const int kb0 = khalf * 32;

    float m_i[2] = {-INFINITY, -INFINITY};
    float l_i[2] = {0.0f, 0.0f};
    float4v acc[2][4];
    #pragma unroll
    for (int mf = 0; mf < 2; ++mf)
        #pragma unroll
        for (int nt = 0; nt < 4; ++nt) acc[mf][nt] = (float4v){0.f, 0.f, 0.f, 0.f};

    for (int kb = kb0; kb < kb0 + 32; ++kb) {
        const long fb = (long)kb * 8;
        short8 kh_[8], kl_[8], vv_[8];
        #pragma unroll
        for (int f = 0; f < 8; ++f)
            kh_[f] = *(const short8*)(KH + (fb + f) * 512 + lo8);
        #pragma unroll
        for (int f = 0; f < 8; ++f)
            kl_[f] = *(const short8*)(KL + (fb + f) * 512 + lo8);
        #pragma unroll
        for (int f = 0; f < 8; ++f)
            vv_[f] = *(const short8*)(VT + (fb + f) * 512 + lo8);

        float4v s[2][4];
        #pragma unroll
        for (int mf = 0; mf < 2; ++mf)
            #pragma unroll
            for (int nt = 0; nt < 4; ++nt) s[mf][nt] = (float4v){0.f, 0.f, 0.f, 0.f};

        __builtin_amdgcn_s_setprio(1);
        #pragma unroll
        for (int mf = 0; mf < 2; ++mf) {
            #pragma unroll
            for (int kc = 0; kc < 2; ++kc)
                #pragma unroll
                for (int nt = 0; nt < 4; ++nt)
                    s[mf][nt] = __builtin_amdgcn_mfma_f32_16x16x32_bf16(
                        kh_[kc * 4 + nt], qh[kc][mf], s[mf][nt], 0, 0, 0);
            #pragma unroll
            for (int kc = 0; kc < 2; ++kc)
                #pragma unroll
                for (int nt = 0; nt < 4; ++nt)
                    s[mf][nt] = __builtin_amdgcn_mfma_f32_16x16x32_bf16(
                        kh_[kc * 4 + nt], ql[kc][mf], s[mf][nt], 0, 0, 0);
            #pragma unroll
            for (int kc = 0; kc < 2; ++kc)
                #pragma unroll
                for (int nt = 0; nt < 4; ++nt)
                    s[mf][nt] = __builtin_amdgcn_mfma_f32_16x16x32_bf16(
                        kl_[kc * 4 + nt], qh[kc][mf], s[mf][nt], 0, 0, 0);
        }
        __builtin_amdgcn_s_setprio(0);

        #pragma unroll
        for (int mf = 0; mf < 2; ++mf) {
            float x0 = fmaxf(fmaxf(s[mf][0][0], s[mf][0][1]),
                             fmaxf(s[mf][0][2], s[mf][0][3]));
            float x1 = fmaxf(fmaxf(s[mf][1][0], s[mf][1][1]),
                             fmaxf(s[mf][1][2], s[mf][1][3]));
            float x2 = fmaxf(fmaxf(s[mf][2][0], s[mf][2][1]),
                             fmaxf(s[mf][2][2], s[mf][2][3]));
            float x3 = fmaxf(fmaxf(s[mf][3][0], s[mf][3][1]),
                             fmaxf(s[mf][3][2], s[mf][3][3]));
            float rm = fmaxf(fmaxf(x0, x1), fmaxf(x2, x3));
            rm = fmaxf(rm, __shfl_xor(rm, 16, 64));
            rm = fmaxf(rm, __shfl_xor(rm, 32, 64));
            const float nm = fmaxf(m_i[mf], rm);
            const float al = __expf(m_i[mf] - nm);
            float p[4][4];
            #pragma unroll
            for (int nt = 0; nt < 4; ++nt)
                #pragma unroll
                for (int rr = 0; rr < 4; ++rr)
                    p[nt][rr] = __expf(s[mf][nt][rr] - nm);
            float y0 = (p[0][0] + p[0][1]) + (p[0][2] + p[0][3]);
            float y1 = (p[1][0] + p[1][1]) + (p[1][2] + p[1][3]);
            float y2 = (p[2][0] + p[2][1]) + (p[2][2] + p[2][3]);
            float y3 = (p[3][0] + p[3][1]) + (p[3][2] + p[3][3]);
            float ps = (y0 + y1) + (y2 + y3);
            ps += __shfl_xor(ps, 16, 64);
            ps += __shfl_xor(ps, 32, 64);
            l_i[mf] = l_i[mf] * al + ps;
            m_i[mf] = nm;
            #pragma unroll
            for (int nt = 0; nt < 4; ++nt) {
                acc[mf][nt][0] *= al; acc[mf][nt][1] *= al;
                acc[mf][nt][2] *= al; acc[mf][nt][3] *= al;
            }
            #pragma unroll
            for (int nt = 0; nt < 4; ++nt) {
                ushort4 pk;
                pk.x = f2us(p[nt][0]); pk.y = f2us(p[nt][1]);
                pk.z = f2us(p[nt][2]); pk.w = f2us(p[nt][3]);
                *(ushort4*)&sP[w][mf * 16 + l16][nt * 16 + quad * 4] = pk;
            }
        }

        __builtin_amdgcn_s_setprio(1);
        #pragma unroll
        for (int mf = 0; mf < 2; ++mf)
            #pragma unroll
            for (int kc = 0; kc < 2; ++kc) {
                short8 aP = *(const short8*)&sP[w][mf * 16 + l16][kc * 32 + quad * 8];
                #pragma unroll
                for (int nt = 0; nt < 4; ++nt)
                    acc[mf][nt] = __builtin_amdgcn_mfma_f32_16x16x32_bf16(
                        vv_[kc * 4 + nt], aP, acc[mf][nt], 0, 0, 0);
            }
        __builtin_amdgcn_s_setprio(0);
    }

    // ---- split-K merge: upper half publishes state, lower half combines.
    if (khalf == 1) {
        #pragma unroll
        for (int mf = 0; mf < 2; ++mf) {
            #pragma unroll
            for (int nt = 0; nt < 4; ++nt)
                *(float4*)&mAcc[wq][mf][nt][l][0] =
                    make_float4(acc[mf][nt][0], acc[mf][nt][1],
                                acc[mf][nt][2], acc[mf][nt][3]);
            mML[wq][mf][0][l] = m_i[mf];
            mML[wq][mf][1][l] = l_i[mf];
        }
    }
    __syncthreads();
    if (khalf == 0) {
        #pragma unroll
        for (int mf = 0; mf < 2; ++mf) {
            const float m1 = mML[wq][mf][0][l];
            const float l1 = mML[wq][mf][1][l];
            const float nm = fmaxf(m_i[mf], m1);
            const float a0 = __expf(m_i[mf] - nm);
            const float a1 = __expf(m1 - nm);
            const float inv = 1.0f / (l_i[mf] * a0 + l1 * a1);
            #pragma unroll
            for (int nt = 0; nt < 4; ++nt) {
                float4 o1 = *(float4*)&mAcc[wq][mf][nt][l][0];
                float4 o = make_float4(
                    (acc[mf][nt][0] * a0 + o1.x * a1) * inv,
                    (acc[mf][nt][1] * a0 + o1.y * a1) * inv,
                    (acc[mf][nt][2] * a0 + o1.z * a1) * inv,
                    (acc[mf][nt][3] * a0 + o1.w * a1) * inv);
                *(float4*)(QZ + (long)(mrow0 + mf * 16 + l16) * 512 + h * 64 +
                           nt * 16 + quad * 4) = o;
            }
        }
    }
}

// ---------------------------------------------------------------------------
// wo2 (MFMA): tmp = Zcat @ WO via bf16 hi/lo 3-product.  grid (8 nb, 64 mb).
// ---------------------------------------------------------------------------
__global__ __launch_bounds__(256) void wo2_kernel(const float* __restrict__ A,
                                                  const float* __restrict__ B,
                                                  float* __restrict__ C) {
    __shared__ u16 sAh[64][72], sAl[64][72];
    __shared__ u16 sBh[64][72], sBl[64][72];
    const int t = threadIdx.x;
    const int w = t >> 6, l = t & 63;
    const int quad = l >> 4, l16 = l & 15;
    const int mw = w * 16;
    const int m0 = blockIdx.y * 64, n0 = blockIdx.x * 64;
    const int ar = t >> 2, ac = (t & 3) << 4;

    float4v acc[4];
    #pragma unroll
    for (int nt = 0; nt < 4; ++nt) acc[nt] = (float4v){0.f, 0.f, 0.f, 0.f};

    for (int k0 = 0; k0 < 512; k0 += 64) {
        #pragma unroll
        for (int u = 0; u < 4; ++u) {
            float4 av = *(const float4*)(A + (long)(m0 + ar) * 512 + k0 + ac + 4 * u);
            float xs[4] = {av.x, av.y, av.z, av.w};
            ushort4 hh, ll;
            u16* hp = (u16*)&hh; u16* lp = (u16*)&ll;
            #pragma unroll
            for (int j = 0; j < 4; ++j) {
                u16 hi = f2us(xs[j]);
                hp[j] = hi;
                lp[j] = f2us(xs[j] - us2f(hi));
            }
            *(ushort4*)&sAh[ar][ac + 4 * u] = hh;
            *(ushort4*)&sAl[ar][ac + 4 * u] = ll;
        }
        {
            const int kr = t >> 2, nc = (t & 3) << 4;
            #pragma unroll
            for (int u = 0; u < 4; ++u) {
                float4 wv = *(const float4*)(B + (long)(k0 + kr) * 512 + n0 + nc + 4 * u);
                float ws4[4] = {wv.x, wv.y, wv.z, wv.w};
                #pragma unroll
                for (int j = 0; j < 4; ++j) {
                    const int n = nc + 4 * u + j;
                    u16 hi = f2us(ws4[j]);
                    sBh[n][kr] = hi;
                    sBl[n][kr] = f2us(ws4[j] - us2f(hi));
                }
            }
        }
        __syncthreads();
        #pragma unroll
        for (int kc = 0; kc < 2; ++kc) {
            short8 ah = *(const short8*)&sAh[mw + l16][kc * 32 + quad * 8];
            short8 al = *(const short8*)&sAl[mw + l16][kc * 32 + quad * 8];
            #pragma unroll
            for (int nt = 0; nt < 4; ++nt) {
                short8 bh = *(const short8*)&sBh[nt * 16 + l16][kc * 32 + quad * 8];
                short8 bl = *(const short8*)&sBl[nt * 16 + l16][kc * 32 + quad * 8];
                acc[nt] = __builtin_amdgcn_mfma_f32_16x16x32_bf16(ah, bh, acc[nt], 0, 0, 0);
                acc[nt] = __builtin_amdgcn_mfma_f32_16x16x32_bf16(ah, bl, acc[nt], 0, 0, 0);
                acc[nt] = __builtin_amdgcn_mfma_f32_16x16x32_bf16(al, bh, acc[nt], 0, 0, 0);
            }
        }
        __syncthreads();
    }
    #pragma unroll
    for (int nt = 0; nt < 4; ++nt)
        #pragma unroll
        for (int rr = 0; rr < 4; ++rr) {
            const int row = m0 + mw + quad * 4 + rr;
            C[(long)row * 512 + n0 + nt * 16 + l16] = acc[nt][rr];
        }
}

// ---------------------------------------------------------------------------
// ln1: Z1 = LN(tmp + E + posenc)*g + be -> d_out f32 AND Z1b bf16 (ws).
// ---------------------------------------------------------------------------
__global__ __launch_bounds__(256) void ln1_kernel(const float* __restrict__ tmp,
                                                  const float* __restrict__ E,
                                                  const float* __restrict__ g,
                                                  const float* __restrict__ be,
                                                  float* __restrict__ out,
                                                  u16* __restrict__ z1b) {
    const int r = blockIdx.x, t = threadIdx.x;
    const long base = (long)r * 512;
    __shared__ float red[256];

    float v0 = tmp[base + t] + E[base + t] + posenc_f(r, t);
    float v1 = tmp[base + t + 256] + E[base + t + 256] + posenc_f(r, t + 256);

    red[t] = v0 + v1; __syncthreads();
    for (int s2 = 128; s2 > 0; s2 >>= 1) {
        if (t < s2) red[t] += red[t + s2];
        __syncthreads();
    }
    const float mean = red[0] * (1.0f / 512.0f);
    __syncthreads();
    float d0 = v0 - mean, d1 = v1 - mean;
    red[t] = d0 * d0 + d1 * d1; __syncthreads();
    for (int s2 = 128; s2 > 0; s2 >>= 1) {
        if (t < s2) red[t] += red[t + s2];
        __syncthreads();
    }
    const float rs = rsqrtf(red[0] * (1.0f / 512.0f) + LN_EPS);
    float o0 = d0 * rs * g[t] + be[t];
    float o1 = d1 * rs * g[t + 256] + be[t + 256];
    out[base + t] = o0;
    out[base + t + 256] = o1;
    z1b[base + t] = f2us(o0);
    z1b[base + t + 256] = f2us(o1);
}

// ---------------------------------------------------------------------------
// wtrans: dst[n][k] (bf16) = src[k][n] (f32).  grid (K/64, N/64).
// ---------------------------------------------------------------------------
__global__ __launch_bounds__(256) void wtrans_kernel(const float* __restrict__ src,
                                                     u16* __restrict__ dst,
                                                     int K, int N) {
    __shared__ float sT[64][65];
    const int t = threadIdx.x;
    const int k0 = blockIdx.x * 64, n0 = blockIdx.y * 64;
    #pragma unroll
    for (int c = 0; c < 4; ++c) {
        const int r = (t >> 4) + c * 16;
        float4 v = *(const float4*)(src + (long)(k0 + r) * N + n0 + ((t & 15) << 2));
        sT[r][((t & 15) << 2) + 0] = v.x;
        sT[r][((t & 15) << 2) + 1] = v.y;
        sT[r][((t & 15) << 2) + 2] = v.z;
        sT[r][((t & 15) << 2) + 3] = v.w;
    }
    __syncthreads();
    const int n = t >> 2, kc = (t & 3) << 4;
    #pragma unroll
    for (int u = 0; u < 4; ++u) {
        ushort4 o;
        o.x = f2us(sT[kc + 4 * u + 0][n]);
        o.y = f2us(sT[kc + 4 * u + 1][n]);
        o.z = f2us(sT[kc + 4 * u + 2][n]);
        o.w = f2us(sT[kc + 4 * u + 3][n]);
        *(ushort4*)(dst + (long)(n0 + n) * K + k0 + kc + 4 * u) = o;
    }
}

// ---------------------------------------------------------------------------
// ffn1 (MFMA): Hff = relu(Z1b @ W1t^T + b1) -> bf16.
// ---------------------------------------------------------------------------
__global__ __launch_bounds__(256) void ffn1_kernel(const u16* __restrict__ A,
                                                   const u16* __restrict__ Bt,
                                                   const float* __restrict__ b1,
                                                   u16* __restrict__ C,
                                                   int m_base) {
    __shared__ u16 sA[64][72], sB[64][72];
    const int t = threadIdx.x;
    const int w = t >> 6, l = t & 63, quad = l >> 4, l16 = l & 15;
    const int mw = w * 16;
    const int m0 = m_base + blockIdx.y * 64, n0 = blockIdx.x * 64;
    const int r = t >> 2, cc = (t & 3) << 4;

    float4v acc[4];
    #pragma unroll
    for (int nt = 0; nt < 4; ++nt) acc[nt] = (float4v){0.f, 0.f, 0.f, 0.f};

    for (int kt = 0; kt < 512; kt += 64) {
        const long aoff = (long)(m0 + r) * 512 + kt + cc;
        *(uint4*)&sA[r][cc]     = *(const uint4*)(A + aoff);
        *(uint4*)&sA[r][cc + 8] = *(const uint4*)(A + aoff + 8);
        const long boff = (long)(n0 + r) * 512 + kt + cc;
        *(uint4*)&sB[r][cc]     = *(const uint4*)(Bt + boff);
        *(uint4*)&sB[r][cc + 8] = *(const uint4*)(Bt + boff + 8);
        __syncthreads();
        #pragma unroll
        for (int kc = 0; kc < 2; ++kc) {
            short8 a = *(const short8*)&sA[mw + l16][kc * 32 + quad * 8];
            #pragma unroll
            for (int nt = 0; nt < 4; ++nt) {
                short8 b = *(const short8*)&sB[nt * 16 + l16][kc * 32 + quad * 8];
                acc[nt] = __builtin_amdgcn_mfma_f32_16x16x32_bf16(a, b, acc[nt], 0, 0, 0);
            }
        }
        __syncthreads();
    }
    #pragma unroll
    for (int rr = 0; rr < 4; ++rr) {
        const int row = blockIdx.y * 64 + mw + quad * 4 + rr;  // chunk-local
        #pragma unroll
        for (int nt = 0; nt < 4; ++nt) {
            const int col = n0 + nt * 16 + l16;
            float v = acc[nt][rr] + b1[col];
            C[(long)row * 2048 + col] = f2us(fmaxf(v, 0.0f));
        }
    }
}

// ---------------------------------------------------------------------------
// ffn2 (MFMA): U = Hff @ W2t^T + b2 -> f32.  Tile 32x64, grid (8 nb, 32 mb)
// = 256 blocks/chunk (verified: ~2x vs 128-block version).
// ---------------------------------------------------------------------------
__global__ __launch_bounds__(256) void ffn2_kernel(const u16* __restrict__ A,
                                                   const u16* __restrict__ Bt,
                                                   const float* __restrict__ b2,
                                                   float* __restrict__ U) {
    __shared__ u16 sA[32][72], sB[64][72];
    const int t = threadIdx.x;
    const int w = t >> 6, l = t & 63, quad = l >> 4, l16 = l & 15;
    const int mf = (w & 1) << 4;     // row-frag base within 32
    const int nh = (w >> 1) << 5;    // col-half base within 64
    const int m0 = blockIdx.y * 32, n0 = blockIdx.x * 64;
    const int ra = t >> 3, ca = (t & 7) << 3;   // A staging: 32x64, 1 uint4/thr
    const int rb = t >> 2, cb = (t & 3) << 4;   // B staging: 64x64, 2 uint4/thr

    float4v acc[2];
    acc[0] = (float4v){0.f, 0.f, 0.f, 0.f};
    acc[1] = (float4v){0.f, 0.f, 0.f, 0.f};

    for (int kt = 0; kt < 2048; kt += 64) {
        *(uint4*)&sA[ra][ca] =
            *(const uint4*)(A + (long)(m0 + ra) * 2048 + kt + ca);
        const long boff = (long)(n0 + rb) * 2048 + kt + cb;
        *(uint4*)&sB[rb][cb]     = *(const uint4*)(Bt + boff);
        *(uint4*)&sB[rb][cb + 8] = *(const uint4*)(Bt + boff + 8);
        __syncthreads();
        #pragma unroll
        for (int kc = 0; kc < 2; ++kc) {
            short8 a = *(const short8*)&sA[mf + l16][kc * 32 + quad * 8];
            #pragma unroll
            for (int nt = 0; nt < 2; ++nt) {
                short8 b = *(const short8*)&sB[nh + nt * 16 + l16][kc * 32 + quad * 8];
                acc[nt] = __builtin_amdgcn_mfma_f32_16x16x32_bf16(a, b, acc[nt], 0, 0, 0);
            }
        }
        __syncthreads();
    }
    #pragma unroll
    for (int rr = 0; rr < 4; ++rr) {
        const int row = m0 + mf + quad * 4 + rr;
        #pragma unroll
        for (int nt = 0; nt < 2; ++nt) {
            const int col = n0 + nh + nt * 16 + l16;
            U[(long)row * 512 + col] = acc[nt][rr] + b2[col];
        }
    }
}

// ---------------------------------------------------------------------------
// ln2: out = LN(U + Z1)*g + be (in place over Z1 rows).
// ---------------------------------------------------------------------------
__global__ __launch_bounds__(256) void ln2_kernel(const float* __restrict__ U,
                                                  const float* __restrict__ Z1,
                                                  const float* __restrict__ g,
                                                  const float* __restrict__ be,
                                                  float* __restrict__ out) {
    const int r = blockIdx.x, t = threadIdx.x;
    const long base = (long)r * 512;
    __shared__ float red[256];

    float v0 = U[base + t] + Z1[base + t];
    float v1 = U[base + t + 256] + Z1[base + t + 256];

    red[t] = v0 + v1; __syncthreads();
    for (int s2 = 128; s2 > 0; s2 >>= 1) {
        if (t < s2) red[t] += red[t + s2];
        __syncthreads();
    }
    const float mean = red[0] * (1.0f / 512.0f);
    __syncthreads();
    float d0 = v0 - mean, d1 = v1 - mean;
    red[t] = d0 * d0 + d1 * d1; __syncthreads();
    for (int s2 = 128; s2 > 0; s2 >>= 1) {
        if (t < s2) red[t] += red[t + s2];
        __syncthreads();
    }
    const float rs = rsqrtf(red[0] * (1.0f / 512.0f) + LN_EPS);
    out[base + t] = d0 * rs * g[t] + be[t];
    out[base + t + 256] = d1 * rs * g[t + 256] + be[t + 256];
}

// ---------------------------------------------------------------------------
// ws timeline (max 14 MB):
//   attention: Khi @0 (4) | Klo @4 (4) | Vt @8 (4)   (fragment layout)
//   wo/ln1:    tmp @0 (8) | Z1b @8 (4)
//   FFN:       W1t @0 (2) | W2t @2 (2) | Hff @4 (4/chunk) | U @12 (2/chunk)
// d_out: Qcat -> Zcat -> Z1 -> out (race-free phase overwrites).
// ---------------------------------------------------------------------------
extern "C" void kernel_launch(void* const* d_in, const int* in_sizes, int n_in,
                              void* d_out, int out_size, void* d_ws, size_t ws_size,
                              hipStream_t stream) {
    float* outf = (float*)d_out;

    static const int exp_sizes[13] = {2097152, 262144, 262144, 262144, 262144,
                                      1048576, 2048, 1048576, 512, 512, 512,
                                      512, 512};
    bool ok = (n_in == 13) && (out_size == 2097152) &&
              (ws_size >= (14ull << 20));
    if (ok) for (int i = 0; i < 13; ++i) if (in_sizes[i] != exp_sizes[i]) ok = false;
    if (!ok) { sentinel_kernel<<<16, 256, 0, stream>>>(outf, 1000.0f); return; }

    const float* E   = (const float*)d_in[0];
    const float* Wq  = (const float*)d_in[1];
    const float* Wk  = (const float*)d_in[2];
    const float* Wv  = (const float*)d_in[3];
    const float* WO  = (const float*)d_in[4];
    const float* W1  = (const float*)d_in[5];
    const float* b1  = (const float*)d_in[6];
    const float* W2  = (const float*)d_in[7];
    const float* b2  = (const float*)d_in[8];
    const float* g1  = (const float*)d_in[9];
    const float* be1 = (const float*)d_in[10];
    const float* g2  = (const float*)d_in[11];
    const float* be2 = (const float*)d_in[12];

    char* base = (char*)d_ws;
    u16*   Khi = (u16*)base;                    // 4 MB
    u16*   Klo = (u16*)(base + (4l << 20));     // 4 MB
    u16*   Vt  = (u16*)(base + (8l << 20));     // 4 MB
    float* tmp = (float*)base;                  // 8 MB (K dead)
    u16*   Z1b = (u16*)(base + (8l << 20));     // 4 MB (Vt dead)
    u16*   W1t = (u16*)base;                    // 2 MB (tmp dead)
    u16*   W2t = (u16*)(base + (2l << 20));     // 2 MB
    u16*   Hff = (u16*)(base + (4l << 20));     // 4 MB / chunk
    float* U   = (float*)(base + (12l << 20));  // 2 MB / chunk

    qkv11_kernel<<<dim3(64, 8), 256, 0, stream>>>(E, Wq, Wk, Wv, outf,
                                                  Khi, Klo, Vt);
    flash14_kernel<<<dim3(256), 512, 0, stream>>>(Khi, Klo, Vt, outf);
    wo2_kernel<<<dim3(8, 64), 256, 0, stream>>>(outf, WO, tmp);
    ln1_kernel<<<4096, 256, 0, stream>>>(tmp, E, g1, be1, outf, Z1b);
    wtrans_kernel<<<dim3(8, 32), 256, 0, stream>>>(W1, W1t, 512, 2048);
    wtrans_kernel<<<dim3(32, 8), 256, 0, stream>>>(W2, W2t, 2048, 512);

    for (int c = 0; c < 4; ++c) {
        ffn1_kernel<<<dim3(32, 16), 256, 0, stream>>>(Z1b, W1t, b1, Hff,
                                                      c * 1024);
        ffn2_kernel<<<dim3(8, 32), 256, 0, stream>>>(Hff, W2t, b2, U);
        ln2_kernel<<<1024, 256, 0, stream>>>(U, outf + (long)c * 1024 * 512,
                                             g2, be2,
                                             outf + (long)c * 1024 * 512);
    }
}

// Round 15
// 365.874 us; speedup vs baseline: 1.0213x; 1.0037x over previous
//
#include <hip/hip_runtime.h>
#include <hip/hip_bf16.h>
#include <cmath>

typedef unsigned short u16;
typedef __attribute__((ext_vector_type(8))) short short8;
typedef __attribute__((ext_vector_type(4))) float float4v;
#define LN_EPS 1e-5f

__device__ __forceinline__ float us2f(u16 u) {
    return __uint_as_float(((unsigned int)u) << 16);
}
__device__ __forceinline__ u16 f2us(float f) {
    __hip_bfloat16 h = __float2bfloat16(f);
    return *(u16*)&h;
}

// Fast posenc: double-precision argument reduction (exact for pos<4096),
// then hardware v_sin_f32/v_cos_f32.
__device__ __forceinline__ float posenc_f(int s, int d) {
    const double c = -9.210340371976184 / 512.0;  // -ln(10000)/512
    double freq_rev = exp((double)(d & ~1) * c) * 0.15915494309189535;
    double rev = (double)s * freq_rev;
    float fr = (float)(rev - floor(rev));
    float ang = 6.28318530717958647692f * fr;
    return (d & 1) ? __cosf(ang) : __sinf(ang);
}

// Wave-level f32 sum over 64 lanes (6 shuffle steps).
__device__ __forceinline__ float wave_sum(float v) {
    v += __shfl_xor(v, 1, 64);
    v += __shfl_xor(v, 2, 64);
    v += __shfl_xor(v, 4, 64);
    v += __shfl_xor(v, 8, 64);
    v += __shfl_xor(v, 16, 64);
    v += __shfl_xor(v, 32, 64);
    return v;
}

__global__ __launch_bounds__(256) void sentinel_kernel(float* out, float v) {
    out[blockIdx.x * 256 + threadIdx.x] = v;
}

// ---------------------------------------------------------------------------
// qkv11: FUSED Q/K/V per block — X (E+posenc, hi/lo) staged ONCE per k-tile,
// three GEMMs against it. Fragment-contiguous K/V epilogues.
// grid (64 mb, 8 h).
// ---------------------------------------------------------------------------
__global__ __launch_bounds__(256) void qkv11_kernel(const float* __restrict__ E,
                                                    const float* __restrict__ Wq,
                                                    const float* __restrict__ Wk,
                                                    const float* __restrict__ Wv,
                                                    float* __restrict__ Qcat,
                                                    u16* __restrict__ Khi,
                                                    u16* __restrict__ Klo,
                                                    u16* __restrict__ Vt) {
    const int h = blockIdx.y;
    const float* W0 = Wq + (long)h * 512 * 64;
    const float* W1 = Wk + (long)h * 512 * 64;
    const float* W2 = Wv + (long)h * 512 * 64;

    __shared__ u16 sAh[64][72], sAl[64][72];
    __shared__ u16 sBh[3][64][72], sBl[3][64][72];
    __shared__ double sFreqRev[512];

    const int t = threadIdx.x;
    const int w = t >> 6, l = t & 63;
    const int quad = l >> 4, l16 = l & 15;
    const int mw = w * 16;
    const int m0 = blockIdx.x * 64;

    {
        const double c = -9.210340371976184 / 512.0;  // -ln(10000)/512
        sFreqRev[t] = exp((double)(t & ~1) * c) * 0.15915494309189535;
        sFreqRev[t + 256] =
            exp((double)((t + 256) & ~1) * c) * 0.15915494309189535;
    }
    __syncthreads();

    const int ar = t >> 2, ac = (t & 3) << 4;   // A staging: row, 16-col base
    const double posd = (double)(m0 + ar);
    const int brow4 = (t >> 4) << 2;            // B staging: 4 k-rows base
    const int bnc = (t & 15) << 2;              // B staging: 4 n-cols base

    float4v acc[3][4];
    #pragma unroll
    for (int ty = 0; ty < 3; ++ty)
        #pragma unroll
        for (int nt = 0; nt < 4; ++nt) acc[ty][nt] = (float4v){0.f, 0.f, 0.f, 0.f};

    for (int k0 = 0; k0 < 512; k0 += 64) {
        // ---- stage A = X[m0+ar][k0+ac .. +15] split hi/lo (ONCE for 3 GEMMs)
        #pragma unroll
        for (int u = 0; u < 4; ++u) {
            float4 ev = *(const float4*)(E + (long)(m0 + ar) * 512 + k0 + ac + 4 * u);
            float xs[4] = {ev.x, ev.y, ev.z, ev.w};
            ushort4 hh, ll;
            u16* hp = (u16*)&hh; u16* lp = (u16*)&ll;
            #pragma unroll
            for (int j = 0; j < 4; ++j) {
                const int col = k0 + ac + 4 * u + j;   // parity == j&1
                double rev = posd * sFreqRev[col];
                float fr = (float)(rev - floor(rev));
                float ang = 6.28318530717958647692f * fr;
                float pe = (j & 1) ? __cosf(ang) : __sinf(ang);
                float x = xs[j] + pe;
                u16 hi = f2us(x);
                hp[j] = hi;
                lp[j] = f2us(x - us2f(hi));
            }
            *(ushort4*)&sAh[ar][ac + 4 * u] = hh;
            *(ushort4*)&sAl[ar][ac + 4 * u] = ll;
        }
        // ---- stage B for 3 types (float4 reads, ushort4 writes along k)
        #pragma unroll
        for (int ty = 0; ty < 3; ++ty) {
            const float* W = (ty == 0 ? W0 : ty == 1 ? W1 : W2);
            float wv4[4][4];
            #pragma unroll
            for (int u = 0; u < 4; ++u)
                *(float4*)&wv4[u][0] =
                    *(const float4*)(W + (long)(k0 + brow4 + u) * 64 + bnc);
            #pragma unroll
            for (int j = 0; j < 4; ++j) {
                ushort4 hh, ll;
                #pragma unroll
                for (int u = 0; u < 4; ++u) {
                    u16 hi = f2us(wv4[u][j]);
                    ((u16*)&hh)[u] = hi;
                    ((u16*)&ll)[u] = f2us(wv4[u][j] - us2f(hi));
                }
                *(ushort4*)&sBh[ty][bnc + j][brow4] = hh;
                *(ushort4*)&sBl[ty][bnc + j][brow4] = ll;
            }
        }
        __syncthreads();
        #pragma unroll
        for (int kc = 0; kc < 2; ++kc) {
            short8 ah = *(const short8*)&sAh[mw + l16][kc * 32 + quad * 8];
            short8 al = *(const short8*)&sAl[mw + l16][kc * 32 + quad * 8];
            #pragma unroll
            for (int ty = 0; ty < 3; ++ty)
                #pragma unroll
                for (int nt = 0; nt < 4; ++nt) {
                    short8 bh = *(const short8*)&sBh[ty][nt * 16 + l16][kc * 32 + quad * 8];
                    short8 bl = *(const short8*)&sBl[ty][nt * 16 + l16][kc * 32 + quad * 8];
                    acc[ty][nt] = __builtin_amdgcn_mfma_f32_16x16x32_bf16(ah, bh, acc[ty][nt], 0, 0, 0);
                    acc[ty][nt] = __builtin_amdgcn_mfma_f32_16x16x32_bf16(ah, bl, acc[ty][nt], 0, 0, 0);
                    acc[ty][nt] = __builtin_amdgcn_mfma_f32_16x16x32_bf16(al, bh, acc[ty][nt], 0, 0, 0);
                }
        }
        __syncthreads();
    }

    // ---- epilogue Q (f32 -> Qcat)
    #pragma unroll
    for (int nt = 0; nt < 4; ++nt)
        #pragma unroll
        for (int rr = 0; rr < 4; ++rr) {
            const int row = m0 + mw + quad * 4 + rr;
            Qcat[(long)row * 512 + h * 64 + nt * 16 + l16] = acc[0][nt][rr];
        }
    // ---- epilogue K (fragment-contiguous hi/lo)
    {
        const int kb = m0 >> 6;
        #pragma unroll
        for (int nt = 0; nt < 4; ++nt) {
            const int fkc = nt >> 1;
            const int fquad = ((nt & 1) << 1) + (l16 >> 3);
            const int fe = l16 & 7;
            const long fbase = ((long)(h * 64 + kb) * 8 + fkc * 4 + w) * 512 +
                               fquad * 128 + fe;
            #pragma unroll
            for (int rr = 0; rr < 4; ++rr) {
                const long off = fbase + (quad * 4 + rr) * 8;
                float v = acc[1][nt][rr];
                u16 hi = f2us(v);
                Khi[off] = hi;
                Klo[off] = f2us(v - us2f(hi));
            }
        }
    }
    // ---- epilogue V (fragment-contiguous V^T)
    {
        const int kb = m0 >> 6;
        const int fkc = w >> 1;
        const int fquad = ((w & 1) << 1) + (quad >> 1);
        const int fe0 = (quad & 1) * 4;
        #pragma unroll
        for (int nt = 0; nt < 4; ++nt) {
            const long off = ((long)(h * 64 + kb) * 8 + fkc * 4 + nt) * 512 +
                             (fquad * 16 + l16) * 8 + fe0;
            ushort4 o;
            o.x = f2us(acc[2][nt][0]); o.y = f2us(acc[2][nt][1]);
            o.z = f2us(acc[2][nt][2]); o.w = f2us(acc[2][nt][3]);
            *(ushort4*)(Vt + off) = o;
        }
    }
}

// ---------------------------------------------------------------------------
// flash14: split-K flash (VERIFIED 87-89us, VGPR 112, no spill). 8 waves:
// wq = w&3 owns 32 q-rows, khalf = w>>2 owns half the K range. LDS padded
// >80 KB so only ONE block/CU fits. Tree reductions, wave-private sP,
// no in-loop barrier, end merge. grid 256, h = bid&7 for XCD colocation.
// ---------------------------------------------------------------------------
__global__ __launch_bounds__(512, 2) void flash14_kernel(const u16* __restrict__ Khi,
                                                         const u16* __restrict__ Klo,
                                                         const u16* __restrict__ Vt,
                                                         float* __restrict__ QZ) {
    const int bid = blockIdx.x;
    const int h = bid & 7;       // XCD-colocated heads
    const int qb = bid >> 3;

    __shared__ u16 sP[8][64][72];                 // 72 KB (padded: block/CU=1)
    __shared__ float mAcc[4][2][4][64][4];        // 32 KB, merge buffer
    __shared__ float mML[4][2][2][64];            // 4 KB, m/l merge

    const int t = threadIdx.x;
    const int w = t >> 6;          // 0..7
    const int wq = w & 3;          // q-row group
    const int khalf = w >> 2;      // K-range half
    const int l = t & 63;
    const int quad = l >> 4;
    const int l16 = l & 15;
    const int mrow0 = qb * 128 + wq * 32;   // wave's first q-row

    // ---- Q fragments in registers (x0.125, hi/lo split), [kc][mf]
    short8 qh[2][2], ql[2][2];
    #pragma unroll
    for (int mf = 0; mf < 2; ++mf)
        #pragma unroll
        for (int kc = 0; kc < 2; ++kc) {
            const float* qp = QZ + (long)(mrow0 + mf * 16 + l16) * 512 + h * 64 +
                              kc * 32 + quad * 8;
            float4 qa = *(const float4*)qp;
            float4 qb4 = *(const float4*)(qp + 4);
            float qv[8] = {qa.x, qa.y, qa.z, qa.w, qb4.x, qb4.y, qb4.z, qb4.w};
            #pragma unroll
            for (int i = 0; i < 8; ++i) {
                float f = qv[i] * 0.125f;
                u16 hi = f2us(f);
                qh[kc][mf][i] = (short)hi;
                ql[kc][mf][i] = (short)f2us(f - us2f(hi));
            }
        }

    const u16* KH = Khi + (long)h * 262144;
    const u16* KL = Klo + (long)h * 262144;
    const u16* VT = Vt + (long)h * 262144;
    const int lo8 = l << 3;   // lane offset in u16 units (16B per lane)
    const int kb0 = khalf * 32;

    float m_i[2] = {-INFINITY, -INFINITY};
    float l_i[2] = {0.0f, 0.0f};
    float4v acc[2][4];
    #pragma unroll
    for (int mf = 0; mf < 2; ++mf)
        #pragma unroll
        for (int nt = 0; nt < 4; ++nt) acc[mf][nt] = (float4v){0.f, 0.f, 0.f, 0.f};

    for (int kb = kb0; kb < kb0 + 32; ++kb) {
        const long fb = (long)kb * 8;
        short8 kh_[8], kl_[8], vv_[8];
        #pragma unroll
        for (int f = 0; f < 8; ++f)
            kh_[f] = *(const short8*)(KH + (fb + f) * 512 + lo8);
        #pragma unroll
        for (int f = 0; f < 8; ++f)
            kl_[f] = *(const short8*)(KL + (fb + f) * 512 + lo8);
        #pragma unroll
        for (int f = 0; f < 8; ++f)
            vv_[f] = *(const short8*)(VT + (fb + f) * 512 + lo8);

        float4v s[2][4];
        #pragma unroll
        for (int mf = 0; mf < 2; ++mf)
            #pragma unroll
            for (int nt = 0; nt < 4; ++nt) s[mf][nt] = (float4v){0.f, 0.f, 0.f, 0.f};

        __builtin_amdgcn_s_setprio(1);
        #pragma unroll
        for (int mf = 0; mf < 2; ++mf) {
            #pragma unroll
            for (int kc = 0; kc < 2; ++kc)
                #pragma unroll
                for (int nt = 0; nt < 4; ++nt)
                    s[mf][nt] = __builtin_amdgcn_mfma_f32_16x16x32_bf16(
                        kh_[kc * 4 + nt], qh[kc][mf], s[mf][nt], 0, 0, 0);
            #pragma unroll
            for (int kc = 0; kc < 2; ++kc)
                #pragma unroll
                for (int nt = 0; nt < 4; ++nt)
                    s[mf][nt] = __builtin_amdgcn_mfma_f32_16x16x32_bf16(
                        kh_[kc * 4 + nt], ql[kc][mf], s[mf][nt], 0, 0, 0);
            #pragma unroll
            for (int kc = 0; kc < 2; ++kc)
                #pragma unroll
                for (int nt = 0; nt < 4; ++nt)
                    s[mf][nt] = __builtin_amdgcn_mfma_f32_16x16x32_bf16(
                        kl_[kc * 4 + nt], qh[kc][mf], s[mf][nt], 0, 0, 0);
        }
        __builtin_amdgcn_s_setprio(0);

        #pragma unroll
        for (int mf = 0; mf < 2; ++mf) {
            float x0 = fmaxf(fmaxf(s[mf][0][0], s[mf][0][1]),
                             fmaxf(s[mf][0][2], s[mf][0][3]));
            float x1 = fmaxf(fmaxf(s[mf][1][0], s[mf][1][1]),
                             fmaxf(s[mf][1][2], s[mf][1][3]));
            float x2 = fmaxf(fmaxf(s[mf][2][0], s[mf][2][1]),
                             fmaxf(s[mf][2][2], s[mf][2][3]));
            float x3 = fmaxf(fmaxf(s[mf][3][0], s[mf][3][1]),
                             fmaxf(s[mf][3][2], s[mf][3][3]));
            float rm = fmaxf(fmaxf(x0, x1), fmaxf(x2, x3));
            rm = fmaxf(rm, __shfl_xor(rm, 16, 64));
            rm = fmaxf(rm, __shfl_xor(rm, 32, 64));
            const float nm = fmaxf(m_i[mf], rm);
            const float al = __expf(m_i[mf] - nm);
            float p[4][4];
            #pragma unroll
            for (int nt = 0; nt < 4; ++nt)
                #pragma unroll
                for (int rr = 0; rr < 4; ++rr)
                    p[nt][rr] = __expf(s[mf][nt][rr] - nm);
            float y0 = (p[0][0] + p[0][1]) + (p[0][2] + p[0][3]);
            float y1 = (p[1][0] + p[1][1]) + (p[1][2] + p[1][3]);
            float y2 = (p[2][0] + p[2][1]) + (p[2][2] + p[2][3]);
            float y3 = (p[3][0] + p[3][1]) + (p[3][2] + p[3][3]);
            float ps = (y0 + y1) + (y2 + y3);
            ps += __shfl_xor(ps, 16, 64);
            ps += __shfl_xor(ps, 32, 64);
            l_i[mf] = l_i[mf] * al + ps;
            m_i[mf] = nm;
            #pragma unroll
            for (int nt = 0; nt < 4; ++nt) {
                acc[mf][nt][0] *= al; acc[mf][nt][1] *= al;
                acc[mf][nt][2] *= al; acc[mf][nt][3] *= al;
            }
            #pragma unroll
            for (int nt = 0; nt < 4; ++nt) {
                ushort4 pk;
                pk.x = f2us(p[nt][0]); pk.y = f2us(p[nt][1]);
                pk.z = f2us(p[nt][2]); pk.w = f2us(p[nt][3]);
                *(ushort4*)&sP[w][mf * 16 + l16][nt * 16 + quad * 4] = pk;
            }
        }

        __builtin_amdgcn_s_setprio(1);
        #pragma unroll
        for (int mf = 0; mf < 2; ++mf)
            #pragma unroll
            for (int kc = 0; kc < 2; ++kc) {
                short8 aP = *(const short8*)&sP[w][mf * 16 + l16][kc * 32 + quad * 8];
                #pragma unroll
                for (int nt = 0; nt < 4; ++nt)
                    acc[mf][nt] = __builtin_amdgcn_mfma_f32_16x16x32_bf16(
                        vv_[kc * 4 + nt], aP, acc[mf][nt], 0, 0, 0);
            }
        __builtin_amdgcn_s_setprio(0);
    }

    // ---- split-K merge: upper half publishes state, lower half combines.
    if (khalf == 1) {
        #pragma unroll
        for (int mf = 0; mf < 2; ++mf) {
            #pragma unroll
            for (int nt = 0; nt < 4; ++nt)
                *(float4*)&mAcc[wq][mf][nt][l][0] =
                    make_float4(acc[mf][nt][0], acc[mf][nt][1],
                                acc[mf][nt][2], acc[mf][nt][3]);
            mML[wq][mf][0][l] = m_i[mf];
            mML[wq][mf][1][l] = l_i[mf];
        }
    }
    __syncthreads();
    if (khalf == 0) {
        #pragma unroll
        for (int mf = 0; mf < 2; ++mf) {
            const float m1 = mML[wq][mf][0][l];
            const float l1 = mML[wq][mf][1][l];
            const float nm = fmaxf(m_i[mf], m1);
            const float a0 = __expf(m_i[mf] - nm);
            const float a1 = __expf(m1 - nm);
            const float inv = 1.0f / (l_i[mf] * a0 + l1 * a1);
            #pragma unroll
            for (int nt = 0; nt < 4; ++nt) {
                float4 o1 = *(float4*)&mAcc[wq][mf][nt][l][0];
                float4 o = make_float4(
                    (acc[mf][nt][0] * a0 + o1.x * a1) * inv,
                    (acc[mf][nt][1] * a0 + o1.y * a1) * inv,
                    (acc[mf][nt][2] * a0 + o1.z * a1) * inv,
                    (acc[mf][nt][3] * a0 + o1.w * a1) * inv);
                *(float4*)(QZ + (long)(mrow0 + mf * 16 + l16) * 512 + h * 64 +
                           nt * 16 + quad * 4) = o;
            }
        }
    }
}

// ---------------------------------------------------------------------------
// wo2 (MFMA): tmp = Zcat @ WO via bf16 hi/lo 3-product.  grid (8 nb, 64 mb).
// ---------------------------------------------------------------------------
__global__ __launch_bounds__(256) void wo2_kernel(const float* __restrict__ A,
                                                  const float* __restrict__ B,
                                                  float* __restrict__ C) {
    __shared__ u16 sAh[64][72], sAl[64][72];
    __shared__ u16 sBh[64][72], sBl[64][72];
    const int t = threadIdx.x;
    const int w = t >> 6, l = t & 63;
    const int quad = l >> 4, l16 = l & 15;
    const int mw = w * 16;
    const int m0 = blockIdx.y * 64, n0 = blockIdx.x * 64;
    const int ar = t >> 2, ac = (t & 3) << 4;

    float4v acc[4];
    #pragma unroll
    for (int nt = 0; nt < 4; ++nt) acc[nt] = (float4v){0.f, 0.f, 0.f, 0.f};

    for (int k0 = 0; k0 < 512; k0 += 64) {
        #pragma unroll
        for (int u = 0; u < 4; ++u) {
            float4 av = *(const float4*)(A + (long)(m0 + ar) * 512 + k0 + ac + 4 * u);
            float xs[4] = {av.x, av.y, av.z, av.w};
            ushort4 hh, ll;
            u16* hp = (u16*)&hh; u16* lp = (u16*)&ll;
            #pragma unroll
            for (int j = 0; j < 4; ++j) {
                u16 hi = f2us(xs[j]);
                hp[j] = hi;
                lp[j] = f2us(xs[j] - us2f(hi));
            }
            *(ushort4*)&sAh[ar][ac + 4 * u] = hh;
            *(ushort4*)&sAl[ar][ac + 4 * u] = ll;
        }
        {
            const int kr = t >> 2, nc = (t & 3) << 4;
            #pragma unroll
            for (int u = 0; u < 4; ++u) {
                float4 wv = *(const float4*)(B + (long)(k0 + kr) * 512 + n0 + nc + 4 * u);
                float ws4[4] = {wv.x, wv.y, wv.z, wv.w};
                #pragma unroll
                for (int j = 0; j < 4; ++j) {
                    const int n = nc + 4 * u + j;
                    u16 hi = f2us(ws4[j]);
                    sBh[n][kr] = hi;
                    sBl[n][kr] = f2us(ws4[j] - us2f(hi));
                }
            }
        }
        __syncthreads();
        #pragma unroll
        for (int kc = 0; kc < 2; ++kc) {
            short8 ah = *(const short8*)&sAh[mw + l16][kc * 32 + quad * 8];
            short8 al = *(const short8*)&sAl[mw + l16][kc * 32 + quad * 8];
            #pragma unroll
            for (int nt = 0; nt < 4; ++nt) {
                short8 bh = *(const short8*)&sBh[nt * 16 + l16][kc * 32 + quad * 8];
                short8 bl = *(const short8*)&sBl[nt * 16 + l16][kc * 32 + quad * 8];
                acc[nt] = __builtin_amdgcn_mfma_f32_16x16x32_bf16(ah, bh, acc[nt], 0, 0, 0);
                acc[nt] = __builtin_amdgcn_mfma_f32_16x16x32_bf16(ah, bl, acc[nt], 0, 0, 0);
                acc[nt] = __builtin_amdgcn_mfma_f32_16x16x32_bf16(al, bh, acc[nt], 0, 0, 0);
            }
        }
        __syncthreads();
    }
    #pragma unroll
    for (int nt = 0; nt < 4; ++nt)
        #pragma unroll
        for (int rr = 0; rr < 4; ++rr) {
            const int row = m0 + mw + quad * 4 + rr;
            C[(long)row * 512 + n0 + nt * 16 + l16] = acc[nt][rr];
        }
}

// ---------------------------------------------------------------------------
// ln1: Z1 = LN(tmp + E + posenc)*g + be -> d_out f32 AND Z1b bf16 (ws).
// Wave-shuffle reduction: 2 barriers instead of 16.
// ---------------------------------------------------------------------------
__global__ __launch_bounds__(256) void ln1_kernel(const float* __restrict__ tmp,
                                                  const float* __restrict__ E,
                                                  const float* __restrict__ g,
                                                  const float* __restrict__ be,
                                                  float* __restrict__ out,
                                                  u16* __restrict__ z1b) {
    const int r = blockIdx.x, t = threadIdx.x;
    const int w = t >> 6;
    const int l = t & 63;
    const long base = (long)r * 512;
    __shared__ float wr1[4], wr2[4];

    float v0 = tmp[base + t] + E[base + t] + posenc_f(r, t);
    float v1 = tmp[base + t + 256] + E[base + t + 256] + posenc_f(r, t + 256);

    float s = wave_sum(v0 + v1);
    if (l == 0) wr1[w] = s;
    __syncthreads();
    const float mean = (wr1[0] + wr1[1] + wr1[2] + wr1[3]) * (1.0f / 512.0f);
    float d0 = v0 - mean, d1 = v1 - mean;
    float q = wave_sum(d0 * d0 + d1 * d1);
    if (l == 0) wr2[w] = q;
    __syncthreads();
    const float rs = rsqrtf((wr2[0] + wr2[1] + wr2[2] + wr2[3]) *
                            (1.0f / 512.0f) + LN_EPS);
    float o0 = d0 * rs * g[t] + be[t];
    float o1 = d1 * rs * g[t + 256] + be[t + 256];
    out[base + t] = o0;
    out[base + t + 256] = o1;
    z1b[base + t] = f2us(o0);
    z1b[base + t + 256] = f2us(o1);
}

// ---------------------------------------------------------------------------
// wtrans: dst[n][k] (bf16) = src[k][n] (f32).  grid (K/64, N/64).
// ---------------------------------------------------------------------------
__global__ __launch_bounds__(256) void wtrans_kernel(const float* __restrict__ src,
                                                     u16* __restrict__ dst,
                                                     int K, int N) {
    __shared__ float sT[64][65];
    const int t = threadIdx.x;
    const int k0 = blockIdx.x * 64, n0 = blockIdx.y * 64;
    #pragma unroll
    for (int c = 0; c < 4; ++c) {
        const int r = (t >> 4) + c * 16;
        float4 v = *(const float4*)(src + (long)(k0 + r) * N + n0 + ((t & 15) << 2));
        sT[r][((t & 15) << 2) + 0] = v.x;
        sT[r][((t & 15) << 2) + 1] = v.y;
        sT[r][((t & 15) << 2) + 2] = v.z;
        sT[r][((t & 15) << 2) + 3] = v.w;
    }
    __syncthreads();
    const int n = t >> 2, kc = (t & 3) << 4;
    #pragma unroll
    for (int u = 0; u < 4; ++u) {
        ushort4 o;
        o.x = f2us(sT[kc + 4 * u + 0][n]);
        o.y = f2us(sT[kc + 4 * u + 1][n]);
        o.z = f2us(sT[kc + 4 * u + 2][n]);
        o.w = f2us(sT[kc + 4 * u + 3][n]);
        *(ushort4*)(dst + (long)(n0 + n) * K + k0 + kc + 4 * u) = o;
    }
}

// ---------------------------------------------------------------------------
// ffn1 (MFMA): Hff = relu(Z1b @ W1t^T + b1) -> bf16.
// ---------------------------------------------------------------------------
__global__ __launch_bounds__(256) void ffn1_kernel(const u16* __restrict__ A,
                                                   const u16* __restrict__ Bt,
                                                   const float* __restrict__ b1,
                                                   u16* __restrict__ C,
                                                   int m_base) {
    __shared__ u16 sA[64][72], sB[64][72];
    const int t = threadIdx.x;
    const int w = t >> 6, l = t & 63, quad = l >> 4, l16 = l & 15;
    const int mw = w * 16;
    const int m0 = m_base + blockIdx.y * 64, n0 = blockIdx.x * 64;
    const int r = t >> 2, cc = (t & 3) << 4;

    float4v acc[4];
    #pragma unroll
    for (int nt = 0; nt < 4; ++nt) acc[nt] = (float4v){0.f, 0.f, 0.f, 0.f};

    for (int kt = 0; kt < 512; kt += 64) {
        const long aoff = (long)(m0 + r) * 512 + kt + cc;
        *(uint4*)&sA[r][cc]     = *(const uint4*)(A + aoff);
        *(uint4*)&sA[r][cc + 8] = *(const uint4*)(A + aoff + 8);
        const long boff = (long)(n0 + r) * 512 + kt + cc;
        *(uint4*)&sB[r][cc]     = *(const uint4*)(Bt + boff);
        *(uint4*)&sB[r][cc + 8] = *(const uint4*)(Bt + boff + 8);
        __syncthreads();
        #pragma unroll
        for (int kc = 0; kc < 2; ++kc) {
            short8 a = *(const short8*)&sA[mw + l16][kc * 32 + quad * 8];
            #pragma unroll
            for (int nt = 0; nt < 4; ++nt) {
                short8 b = *(const short8*)&sB[nt * 16 + l16][kc * 32 + quad * 8];
                acc[nt] = __builtin_amdgcn_mfma_f32_16x16x32_bf16(a, b, acc[nt], 0, 0, 0);
            }
        }
        __syncthreads();
    }
    #pragma unroll
    for (int rr = 0; rr < 4; ++rr) {
        const int row = blockIdx.y * 64 + mw + quad * 4 + rr;  // chunk-local
        #pragma unroll
        for (int nt = 0; nt < 4; ++nt) {
            const int col = n0 + nt * 16 + l16;
            float v = acc[nt][rr] + b1[col];
            C[(long)row * 2048 + col] = f2us(fmaxf(v, 0.0f));
        }
    }
}

// ---------------------------------------------------------------------------
// ffn2 (MFMA): U = Hff @ W2t^T + b2 -> f32.  Tile 32x64, grid (8 nb, 32 mb)
// = 256 blocks/chunk (verified: ~2x vs 128-block version).
// ---------------------------------------------------------------------------
__global__ __launch_bounds__(256) void ffn2_kernel(const u16* __restrict__ A,
                                                   const u16* __restrict__ Bt,
                                                   const float* __restrict__ b2,
                                                   float* __restrict__ U) {
    __shared__ u16 sA[32][72], sB[64][72];
    const int t = threadIdx.x;
    const int w = t >> 6, l = t & 63, quad = l >> 4, l16 = l & 15;
    const int mf = (w & 1) << 4;     // row-frag base within 32
    const int nh = (w >> 1) << 5;    // col-half base within 64
    const int m0 = blockIdx.y * 32, n0 = blockIdx.x * 64;
    const int ra = t >> 3, ca = (t & 7) << 3;   // A staging: 32x64, 1 uint4/thr
    const int rb = t >> 2, cb = (t & 3) << 4;   // B staging: 64x64, 2 uint4/thr

    float4v acc[2];
    acc[0] = (float4v){0.f, 0.f, 0.f, 0.f};
    acc[1] = (float4v){0.f, 0.f, 0.f, 0.f};

    for (int kt = 0; kt < 2048; kt += 64) {
        *(uint4*)&sA[ra][ca] =
            *(const uint4*)(A + (long)(m0 + ra) * 2048 + kt + ca);
        const long boff = (long)(n0 + rb) * 2048 + kt + cb;
        *(uint4*)&sB[rb][cb]     = *(const uint4*)(Bt + boff);
        *(uint4*)&sB[rb][cb + 8] = *(const uint4*)(Bt + boff + 8);
        __syncthreads();
        #pragma unroll
        for (int kc = 0; kc < 2; ++kc) {
            short8 a = *(const short8*)&sA[mf + l16][kc * 32 + quad * 8];
            #pragma unroll
            for (int nt = 0; nt < 2; ++nt) {
                short8 b = *(const short8*)&sB[nh + nt * 16 + l16][kc * 32 + quad * 8];
                acc[nt] = __builtin_amdgcn_mfma_f32_16x16x32_bf16(a, b, acc[nt], 0, 0, 0);
            }
        }
        __syncthreads();
    }
    #pragma unroll
    for (int rr = 0; rr < 4; ++rr) {
        const int row = m0 + mf + quad * 4 + rr;
        #pragma unroll
        for (int nt = 0; nt < 2; ++nt) {
            const int col = n0 + nh + nt * 16 + l16;
            U[(long)row * 512 + col] = acc[nt][rr] + b2[col];
        }
    }
}

// ---------------------------------------------------------------------------
// ln2: out = LN(U + Z1)*g + be.  Wave-shuffle reduction: 2 barriers.
// ---------------------------------------------------------------------------
__global__ __launch_bounds__(256) void ln2_kernel(const float* __restrict__ U,
                                                  const float* __restrict__ Z1,
                                                  const float* __restrict__ g,
                                                  const float* __restrict__ be,
                                                  float* __restrict__ out) {
    const int r = blockIdx.x, t = threadIdx.x;
    const int w = t >> 6;
    const int l = t & 63;
    const long base = (long)r * 512;
    __shared__ float wr1[4], wr2[4];

    float v0 = U[base + t] + Z1[base + t];
    float v1 = U[base + t + 256] + Z1[base + t + 256];

    float s = wave_sum(v0 + v1);
    if (l == 0) wr1[w] = s;
    __syncthreads();
    const float mean = (wr1[0] + wr1[1] + wr1[2] + wr1[3]) * (1.0f / 512.0f);
    float d0 = v0 - mean, d1 = v1 - mean;
    float q = wave_sum(d0 * d0 + d1 * d1);
    if (l == 0) wr2[w] = q;
    __syncthreads();
    const float rs = rsqrtf((wr2[0] + wr2[1] + wr2[2] + wr2[3]) *
                            (1.0f / 512.0f) + LN_EPS);
    out[base + t] = d0 * rs * g[t] + be[t];
    out[base + t + 256] = d1 * rs * g[t + 256] + be[t + 256];
}

// ---------------------------------------------------------------------------
// ws timeline (max 14 MB):
//   attention: Khi @0 (4) | Klo @4 (4) | Vt @8 (4)   (fragment layout)
//   wo/ln1:    tmp @0 (8) | Z1b @8 (4)
//   FFN:       W1t @0 (2) | W2t @2 (2) | Hff @4 (4/chunk) | U @12 (2/chunk)
// d_out: Qcat -> Zcat -> Z1 -> out (race-free phase overwrites).
// ---------------------------------------------------------------------------
extern "C" void kernel_launch(void* const* d_in, const int* in_sizes, int n_in,
                              void* d_out, int out_size, void* d_ws, size_t ws_size,
                              hipStream_t stream) {
    float* outf = (float*)d_out;

    static const int exp_sizes[13] = {2097152, 262144, 262144, 262144, 262144,
                                      1048576, 2048, 1048576, 512, 512, 512,
                                      512, 512};
    bool ok = (n_in == 13) && (out_size == 2097152) &&
              (ws_size >= (14ull << 20));
    if (ok) for (int i = 0; i < 13; ++i) if (in_sizes[i] != exp_sizes[i]) ok = false;
    if (!ok) { sentinel_kernel<<<16, 256, 0, stream>>>(outf, 1000.0f); return; }

    const float* E   = (const float*)d_in[0];
    const float* Wq  = (const float*)d_in[1];
    const float* Wk  = (const float*)d_in[2];
    const float* Wv  = (const float*)d_in[3];
    const float* WO  = (const float*)d_in[4];
    const float* W1  = (const float*)d_in[5];
    const float* b1  = (const float*)d_in[6];
    const float* W2  = (const float*)d_in[7];
    const float* b2  = (const float*)d_in[8];
    const float* g1  = (const float*)d_in[9];
    const float* be1 = (const float*)d_in[10];
    const float* g2  = (const float*)d_in[11];
    const float* be2 = (const float*)d_in[12];

    char* base = (char*)d_ws;
    u16*   Khi = (u16*)base;                    // 4 MB
    u16*   Klo = (u16*)(base + (4l << 20));     // 4 MB
    u16*   Vt  = (u16*)(base + (8l << 20));     // 4 MB
    float* tmp = (float*)base;                  // 8 MB (K dead)
    u16*   Z1b = (u16*)(base + (8l << 20));     // 4 MB (Vt dead)
    u16*   W1t = (u16*)base;                    // 2 MB (tmp dead)
    u16*   W2t = (u16*)(base + (2l << 20));     // 2 MB
    u16*   Hff = (u16*)(base + (4l << 20));     // 4 MB / chunk
    float* U   = (float*)(base + (12l << 20));  // 2 MB / chunk

    qkv11_kernel<<<dim3(64, 8), 256, 0, stream>>>(E, Wq, Wk, Wv, outf,
                                                  Khi, Klo, Vt);
    flash14_kernel<<<dim3(256), 512, 0, stream>>>(Khi, Klo, Vt, outf);
    wo2_kernel<<<dim3(8, 64), 256, 0, stream>>>(outf, WO, tmp);
    ln1_kernel<<<4096, 256, 0, stream>>>(tmp, E, g1, be1, outf, Z1b);
    wtrans_kernel<<<dim3(8, 32), 256, 0, stream>>>(W1, W1t, 512, 2048);
    wtrans_kernel<<<dim3(32, 8), 256, 0, stream>>>(W2, W2t, 2048, 512);

    for (int c = 0; c < 4; ++c) {
        ffn1_kernel<<<dim3(32, 16), 256, 0, stream>>>(Z1b, W1t, b1, Hff,
                                                      c * 1024);
        ffn2_kernel<<<dim3(8, 32), 256, 0, stream>>>(Hff, W2t, b2, U);
        ln2_kernel<<<1024, 256, 0, stream>>>(U, outf + (long)c * 1024 * 512,
                                             g2, be2,
                                             outf + (long)c * 1024 * 512);
    }
}